// Round 11
// baseline (201.837 us; speedup 1.0000x reference)
//
#include <hip/hip_runtime.h>

typedef __attribute__((ext_vector_type(8))) short short8;
typedef __attribute__((ext_vector_type(4))) float f32x4;

#define MFMA_BF16 __builtin_amdgcn_mfma_f32_16x16x32_bf16

__device__ __forceinline__ unsigned short f2bf(float f) {
  unsigned u = __builtin_bit_cast(unsigned, f);
  u += 0x7fffu + ((u >> 16) & 1u);
  return (unsigned short)(u >> 16);
}

__device__ __forceinline__ unsigned cvtpk(float a, float b) {  // lo=bf16(a), hi=bf16(b)
  unsigned r;
  asm("v_cvt_pk_bf16_f32 %0, %1, %2" : "=v"(r) : "v"(a), "v"(b));
  return r;
}

// ---------------- fused fp32 -> bf16 convert for all 5 inputs ----------------
__global__ __launch_bounds__(256) void f2b5_kernel(const float* __restrict__ x,
                                                   const float* __restrict__ wq,
                                                   const float* __restrict__ wk,
                                                   const float* __restrict__ wv,
                                                   const float* __restrict__ wo,
                                                   unsigned short* __restrict__ xb,
                                                   unsigned short* __restrict__ wb,
                                                   unsigned short* __restrict__ wob) {
  const int b = blockIdx.x;
  const float* src;
  unsigned short* dst;
  int base;
  if (b < 4096)      { src = x;  dst = xb;                base = b; }
  else if (b < 8192) { src = wq; dst = wb;                base = b - 4096; }
  else if (b < 9216) { src = wk; dst = wb + 2048 * 2048;  base = b - 8192; }
  else if (b < 10240){ src = wv; dst = wb + 2560 * 2048;  base = b - 9216; }
  else               { src = wo; dst = wob;               base = b - 10240; }
  const int i = base * 256 + threadIdx.x;
  const float4 v = ((const float4*)src)[i];
  ushort4 o = make_ushort4(f2bf(v.x), f2bf(v.y), f2bf(v.z), f2bf(v.w));
  ((ushort4*)dst)[i] = o;
}

// ---------------- RoPE trig table: [N][32] cos/sin (f64 once, tiny) ----------------
__global__ __launch_bounds__(256) void trig_kernel(float* __restrict__ cosT, float* __restrict__ sinT) {
  int i = blockIdx.x * 256 + threadIdx.x;  // [0, 2048*32)
  int n = i >> 5, f = i & 31;
  double ang = (double)n * pow(10000.0, -(double)f / 32.0);
  cosT[i] = (float)cos(ang);
  sinT[i] = (float)sin(ang);
}

// ---------------- split-K partial reduce: out = a + b (float4 x2 per thread) ----------------
__global__ __launch_bounds__(256) void add2_kernel(const float* __restrict__ a,
                                                   const float* __restrict__ b,
                                                   float* __restrict__ o) {
  int i = blockIdx.x * 256 + threadIdx.x;
#pragma unroll
  for (int s = 0; s < 2; ++s) {
    const float4 u = ((const float4*)a)[i], v = ((const float4*)b)[i];
    ((float4*)o)[i] = make_float4(u.x + v.x, u.y + v.y, u.z + v.z, u.w + v.w);
    i += 524288;
  }
}

// ---------------- bf16 NT GEMM, 2-phase double-buffered, split-K to partials ----------------
// C_z[M][N] = A[M][Kchunk_z] * B[N][Kchunk_z]^T ; z-slice writes C + z*M*N (plain stores).
// LDS chunk-XOR swizzle: LDS chunk c of row r holds global chunk c^(r&3)  (pre-swizzled src).
__global__ __launch_bounds__(256) void gemm_bt(const short* __restrict__ A,
                                               const short* __restrict__ B,
                                               float* __restrict__ C,
                                               int M, int N, int K, int KC) {
  __shared__ __align__(16) short As[2][128 * 32];
  __shared__ __align__(16) short Bs[2][128 * 32];
  const int tid = threadIdx.x;
  const int w = tid >> 6, lane = tid & 63;
  const int fr = lane & 15, fs = lane >> 4;
  const size_t brow = (size_t)blockIdx.y * 128, bcol = (size_t)blockIdx.x * 128;
  const int wr = (w >> 1) * 64, wc = (w & 1) * 64;
  const int lr = tid >> 2;          // staging row 0..63 (+64 for 2nd issue)
  const int lcS = ((tid & 3) ^ (lr & 3)) * 8;  // pre-swizzled source chunk (8 bf16 = 16B)
  const int ks = blockIdx.z * KC;
  C += (size_t)blockIdx.z * ((size_t)M * N);   // partial buffer for this z-slice
  const short* ga = A + (brow + lr) * (size_t)K + lcS + ks;
  const short* gb = B + (bcol + lr) * (size_t)K + lcS + ks;
  f32x4 acc[4][4] = {};

  auto stage = [&](int sb, int k0) {
    short* lA = As[sb] + w * 512;   // wave-uniform LDS dest (HW: base + lane*16B)
    short* lB = Bs[sb] + w * 512;
    __builtin_amdgcn_global_load_lds((__attribute__((address_space(1))) void*)(ga + k0),
                                     (__attribute__((address_space(3))) void*)(lA), 16, 0, 0);
    __builtin_amdgcn_global_load_lds((__attribute__((address_space(1))) void*)(ga + (size_t)64 * K + k0),
                                     (__attribute__((address_space(3))) void*)(lA + 2048), 16, 0, 0);
    __builtin_amdgcn_global_load_lds((__attribute__((address_space(1))) void*)(gb + k0),
                                     (__attribute__((address_space(3))) void*)(lB), 16, 0, 0);
    __builtin_amdgcn_global_load_lds((__attribute__((address_space(1))) void*)(gb + (size_t)64 * K + k0),
                                     (__attribute__((address_space(3))) void*)(lB + 2048), 16, 0, 0);
  };

  const int nk = KC >> 5;
  stage(0, 0);
  __syncthreads();                  // drain prologue loads
  int buf = 0;
  for (int t = 0; t < nk; ++t) {
    if (t + 1 < nk) stage(buf ^ 1, (t + 1) * 32);  // issue next-tile loads (in flight over MFMA)
    short8 af[4], bfr[4];
#pragma unroll
    for (int m = 0; m < 4; ++m)
      af[m] = *(const short8*)(As[buf] + (wr + m * 16 + fr) * 32 + ((fs ^ (fr & 3)) * 8));
#pragma unroll
    for (int n = 0; n < 4; ++n)
      bfr[n] = *(const short8*)(Bs[buf] + (wc + n * 16 + fr) * 32 + ((fs ^ (fr & 3)) * 8));
#pragma unroll
    for (int m = 0; m < 4; ++m)
#pragma unroll
      for (int n = 0; n < 4; ++n)
        acc[m][n] = MFMA_BF16(af[m], bfr[n], acc[m][n], 0, 0, 0);
    __syncthreads();                // vmcnt(0)+barrier: next tile staged, this buf free
    buf ^= 1;
  }
#pragma unroll
  for (int m = 0; m < 4; ++m)
#pragma unroll
    for (int n = 0; n < 4; ++n)
#pragma unroll
      for (int j = 0; j < 4; ++j)
        C[(brow + wr + m * 16 + fs * 4 + j) * (size_t)N + bcol + wc + n * 16 + fr] = acc[m][n][j];
}

// ---------------- fused split-K reduce + QK-RMSNorm + RoPE + head-major scatter ----------------
// qkv partials: qkvA/qkvB [N][3072] fp32 (q 0:2048 | k 2048:2560 | v 2560:3072); row = A + B
// qb: [H][N][64] bf16 (Q pre-scaled by D^-0.5 * log2e) ; kb: [KV][N][64] ; vbt: [KV][64][N]
__global__ __launch_bounds__(256) void prep_kernel(const float* __restrict__ qkv,
                                                   const float* __restrict__ qw,
                                                   const float* __restrict__ kw,
                                                   const float* __restrict__ cosT,
                                                   const float* __restrict__ sinT,
                                                   short* __restrict__ qb,
                                                   short* __restrict__ kb,
                                                   short* __restrict__ vbt) {
  const int n = blockIdx.x, t = threadIdx.x;
  const int w = t >> 6, lane = t & 63;
  __shared__ float redq[4], redk[4];
  const float* rowA = qkv + (size_t)n * 3072;
  const float* rowB = rowA + 6291456;  // second z-partial
  const float* cT = cosT + n * 32;
  const float* sT = sinT + n * 32;
  // --- Q: 2048 elems, 8/thread, norm over full 2048 ---
  const float4* r4a = (const float4*)rowA;
  const float4* r4b = (const float4*)rowB;
  float4 a0 = r4a[t * 2], a1 = r4b[t * 2];
  float4 b0 = r4a[t * 2 + 1], b1 = r4b[t * 2 + 1];
  float4 a = make_float4(a0.x + a1.x, a0.y + a1.y, a0.z + a1.z, a0.w + a1.w);
  float4 b = make_float4(b0.x + b1.x, b0.y + b1.y, b0.z + b1.z, b0.w + b1.w);
  float ss = a.x*a.x + a.y*a.y + a.z*a.z + a.w*a.w + b.x*b.x + b.y*b.y + b.z*b.z + b.w*b.w;
#pragma unroll
  for (int off = 32; off > 0; off >>= 1) ss += __shfl_xor(ss, off);
  if (lane == 0) redq[w] = ss;
  __syncthreads();
  // fold D^-0.5 and log2(e) (scores in log2-domain for exp2-based softmax)
  float rsq = rsqrtf((redq[0] + redq[1] + redq[2] + redq[3]) * (1.0f / 2048.f) + 1e-6f)
              * 0.125f * 1.44269504088896f;
  const int base = t * 8;
  float y[8] = {a.x, a.y, a.z, a.w, b.x, b.y, b.z, b.w};
#pragma unroll
  for (int e = 0; e < 8; ++e) y[e] *= rsq * qw[base + e];
  short8 ov;
  const int dbase = base & 63;
#pragma unroll
  for (int p = 0; p < 4; ++p) {
    float c = cT[(dbase >> 1) + p], s = sT[(dbase >> 1) + p];
    float x1 = y[2 * p], x2 = y[2 * p + 1];
    ov[2 * p]     = (short)f2bf(x1 * c - x2 * s);
    ov[2 * p + 1] = (short)f2bf(x1 * s + x2 * c);
  }
  const int h = base >> 6;
  *(short8*)(qb + ((size_t)h * 2048 + n) * 64 + dbase) = ov;
  // --- K: 512 elems, 2/thread, norm over full 512 ---
  const int ki = t * 2;
  float2 k0 = *(const float2*)(rowA + 2048 + ki);
  float2 k1 = *(const float2*)(rowB + 2048 + ki);
  float2 kv2 = make_float2(k0.x + k1.x, k0.y + k1.y);
  float ssk = kv2.x * kv2.x + kv2.y * kv2.y;
#pragma unroll
  for (int off = 32; off > 0; off >>= 1) ssk += __shfl_xor(ssk, off);
  if (lane == 0) redk[w] = ssk;
  __syncthreads();
  float rsk = rsqrtf((redk[0] + redk[1] + redk[2] + redk[3]) * (1.0f / 512.f) + 1e-6f);
  float z0 = kv2.x * rsk * kw[ki], z1 = kv2.y * rsk * kw[ki + 1];
  const int kd = ki & 63, kvh = ki >> 6;
  {
    float c = cT[kd >> 1], s = sT[kd >> 1];
    ushort2 o2 = make_ushort2(f2bf(z0 * c - z1 * s), f2bf(z0 * s + z1 * c));
    *(ushort2*)(kb + ((size_t)kvh * 2048 + n) * 64 + kd) = o2;
  }
  // --- V: bf16 + transpose store [KV][64][N] ---
  float2 v0 = *(const float2*)(rowA + 2560 + ki);
  float2 v1 = *(const float2*)(rowB + 2560 + ki);
  vbt[((size_t)kvh * 64 + kd) * 2048 + n]       = (short)f2bf(v0.x + v1.x);
  vbt[((size_t)kvh * 64 + kd + 1) * 2048 + n]   = (short)f2bf(v0.y + v1.y);
}

// ---------------- causal GQA flash attention v9: v7 + V-direct-to-registers ----------------
// 1024 blocks (head, qblk) longest-first; 4 waves * 16 q-rows; KVBLK=64.
// K double-buffered in LDS (global_load_lds w=16, pre-swizzled src) — proven pipeline.
// V loads straight from L2 into 32 VGPRs, issued loop-top (T14 issue-early/consume-late):
// vbt region is 256KB/kv-head shared by 128 blocks, L2-hot; QK+softmax (~400cy) hides latency.
// LDS 24 KB -> 5-6 blocks/CU (was 4 at 40 KB). Swapped MFMA(K,Q) softmax core from v7.
__global__ __launch_bounds__(256, 5) void attn_kernel(const short* __restrict__ qb,
                                                      const short* __restrict__ kb,
                                                      const short* __restrict__ vbt,
                                                      short* __restrict__ ab) {
  const int bid = blockIdx.x;
  const int h = bid & 31;
  const int qblk = 31 - (bid >> 5);       // longest blocks dispatch first
  const int kvh = h >> 2;                 // G=4
  const int tid = threadIdx.x;
  const int w = tid >> 6, lane = tid & 63;
  const int fr = lane & 15, fs = lane >> 4;
  const int q0w = qblk * 64 + w * 16;
  const int q_lane = q0w + fr;            // this lane's q row
  __shared__ __align__(16) short Ks[2][64][64];  // [buf][kv][d], chunk c holds global chunk c^(kv&7)
  __shared__ __align__(16) short Ps[4][16][64];  // per-wave P[q][kv], u64-slot swizzled by (q&7)<<1
  const short* Kb = kb + (size_t)kvh * 2048 * 64;
  const short* Vb = vbt + (size_t)kvh * 64 * 2048;
  // Q fragments (B-operand): lane fr <-> q row, elements fs*8+j <-> d (pre-scaled /8*log2e)
  short8 qf[2];
  {
    const short* qrow = qb + ((size_t)h * 2048 + q_lane) * 64;
    qf[0] = *(const short8*)(qrow + fs * 8);
    qf[1] = *(const short8*)(qrow + 32 + fs * 8);
  }
  short8 ones8;
#pragma unroll
  for (int e = 0; e < 8; ++e) ones8[e] = (short)0x3F80;  // bf16 1.0
  f32x4 accO[4] = {};                     // O^T: lane q=fr, d = dt*16 + fs*4 + j
  f32x4 lacc = {};                        // row-sum via ones-MFMA (all regs equal)
  float m = -1e30f;                       // scalar running max for this lane's q row
  short* prow = &Ps[w][fr][0];
  const int swz = (fr & 7) << 1;          // u64-slot XOR (bit0 free -> b128 reads contiguous)

  const int rS = lane >> 3;               // staging row within 8-row strip
  const int cS = (lane & 7) ^ rS;         // pre-swizzled source chunk
  auto stageK = [&](int sb, int kv0s) {
#pragma unroll
    for (int i = 0; i < 2; ++i) {
      int r = i * 32 + w * 8 + rS;        // r & 7 == rS
      __builtin_amdgcn_global_load_lds(
          (__attribute__((address_space(1))) void*)(Kb + (size_t)(kv0s + r) * 64 + cS * 8),
          (__attribute__((address_space(3))) void*)(&Ks[sb][0][0] + i * 2048 + w * 512), 16, 0, 0);
    }
  };

  const int ntiles = qblk + 1;
  int buf = 0;
  stageK(0, 0);
  __syncthreads();
  for (int t = 0; t < ntiles; ++t) {
    const int kv0 = t * 64;
    // ---- V fragments direct from L2, issued FIRST (oldest in vmcnt queue ->
    //      PV's wait is vmcnt(2), keeping the K prefetch in flight) ----
    short8 vf[4][2];
#pragma unroll
    for (int dt = 0; dt < 4; ++dt) {
      const short* vr = Vb + (size_t)(dt * 16 + fr) * 2048 + kv0;
      vf[dt][0] = *(const short8*)(vr + fs * 8);
      vf[dt][1] = *(const short8*)(vr + 32 + fs * 8);
    }
    if (t + 1 < ntiles) stageK(buf ^ 1, (t + 1) * 64);
    const short* KsB = &Ks[buf][0][0];
    const int sw = (fr & 7);
    // ---- QK^T swapped: sc[ct][j] = S[kv=kv0+ct*16+fs*4+j][q=q_lane] (log2-domain) ----
    f32x4 sc[4];
#pragma unroll
    for (int ct = 0; ct < 4; ++ct) {
      const int rk = ct * 16 + fr;
      short8 kf0 = *(const short8*)(KsB + rk * 64 + ((fs ^ sw) * 8));
      short8 kf1 = *(const short8*)(KsB + rk * 64 + (((4 + fs) ^ sw) * 8));
      f32x4 a = {};
      a = MFMA_BF16(kf0, qf[0], a, 0, 0, 0);
      a = MFMA_BF16(kf1, qf[1], a, 0, 0, 0);
      sc[ct] = a;
    }
    // ---- causal mask (diagonal tile only): kv > q ----
    if (t == qblk) {
#pragma unroll
      for (int ct = 0; ct < 4; ++ct) {
        const int kvb = kv0 + ct * 16 + fs * 4;
#pragma unroll
        for (int j = 0; j < 4; ++j)
          if (kvb + j > q_lane) sc[ct][j] = -1e30f;
      }
    }
    // ---- row max: 15 in-reg fmax + 2 shfl (lanes fr,fr+16,fr+32,fr+48 share q) ----
    float v0m = fmaxf(fmaxf(sc[0][0], sc[0][1]), fmaxf(sc[0][2], sc[0][3]));
    float v1m = fmaxf(fmaxf(sc[1][0], sc[1][1]), fmaxf(sc[1][2], sc[1][3]));
    float v2m = fmaxf(fmaxf(sc[2][0], sc[2][1]), fmaxf(sc[2][2], sc[2][3]));
    float v3m = fmaxf(fmaxf(sc[3][0], sc[3][1]), fmaxf(sc[3][2], sc[3][3]));
    float vmax = fmaxf(fmaxf(v0m, v1m), fmaxf(v2m, v3m));
    vmax = fmaxf(vmax, __shfl_xor(vmax, 16));
    vmax = fmaxf(vmax, __shfl_xor(vmax, 32));
    // ---- defer-max (T13, THR=8 in log2-domain -> P <= 256) ----
    if (!__all(vmax - m <= 8.0f)) {
      float mn = fmaxf(m, vmax);
      float resc = exp2f(m - mn);
      m = mn;
      lacc *= resc;
#pragma unroll
      for (int dt = 0; dt < 4; ++dt)
#pragma unroll
        for (int j = 0; j < 4; ++j) accO[dt][j] *= resc;
    }
    // ---- P = exp2(sc - m); cvt_pk pack; 4x swizzled ds_write_b64 ----
#pragma unroll
    for (int ct = 0; ct < 4; ++ct) {
      uint2 pk;
      pk.x = cvtpk(exp2f(sc[ct][0] - m), exp2f(sc[ct][1] - m));
      pk.y = cvtpk(exp2f(sc[ct][2] - m), exp2f(sc[ct][3] - m));
      *(uint2*)(prow + (((ct * 4 + fs) ^ swz) * 4)) = pk;
    }
    // ---- PV + row-sum: pa = B-frag of P^T (lane fr <-> q, elements fs*8+j <-> kv) ----
    short8 pa[2];
#pragma unroll
    for (int s = 0; s < 2; ++s)
      pa[s] = *(const short8*)(prow + (((s * 8 + fs * 2) ^ swz) * 4));
    __builtin_amdgcn_s_setprio(1);
    lacc = MFMA_BF16(ones8, pa[0], lacc, 0, 0, 0);
    lacc = MFMA_BF16(ones8, pa[1], lacc, 0, 0, 0);
#pragma unroll
    for (int dt = 0; dt < 4; ++dt) {
      accO[dt] = MFMA_BF16(vf[dt][0], pa[0], accO[dt], 0, 0, 0);
      accO[dt] = MFMA_BF16(vf[dt][1], pa[1], accO[dt], 0, 0, 0);
    }
    __builtin_amdgcn_s_setprio(0);
    __syncthreads();
    buf ^= 1;
  }
  // ---- epilogue: O = O^T normalized; packed 8B stores ----
  const float inv = 1.0f / lacc[0];
  short* orow = ab + (size_t)q_lane * 2048 + h * 64;
#pragma unroll
  for (int dt = 0; dt < 4; ++dt) {
    uint2 o;
    o.x = cvtpk(accO[dt][0] * inv, accO[dt][1] * inv);
    o.y = cvtpk(accO[dt][2] * inv, accO[dt][3] * inv);
    *(uint2*)(orow + dt * 16 + fs * 4) = o;
  }
}

extern "C" void kernel_launch(void* const* d_in, const int* in_sizes, int n_in,
                              void* d_out, int out_size, void* d_ws, size_t ws_size,
                              hipStream_t stream) {
  const float* x  = (const float*)d_in[0];
  const float* wq = (const float*)d_in[1];
  const float* wk = (const float*)d_in[2];
  const float* wv = (const float*)d_in[3];
  const float* wo = (const float*)d_in[4];
  const float* qw = (const float*)d_in[5];
  const float* kw = (const float*)d_in[6];
  float* out = (float*)d_out;
  char* ws = (char*)d_ws;
  short* xb    = (short*)(ws + 0);          // 8 MB  : x bf16, then attn-out bf16
  short* wb    = (short*)(ws + 8388608);    // 12 MB : [wq;wk;wv] bf16 [3072][2048]
  short* wob   = (short*)(ws + 20971520);   // 8 MB  : wo bf16
  float* qkvfA = (float*)(ws + 29360128);   // 24 MB : qkv z0 partial [2048][3072] f32
  float* qkvfB = (float*)(ws + 54525952);   // 24 MB : qkv z1 partial (contiguous after A)
  short* qb    = (short*)(ws + 79691776);   // 8 MB  : q roped+scaled [32][2048][64]
  short* kb    = (short*)(ws + 88080384);   // 2 MB  : k roped [8][2048][64]
  short* vbt   = (short*)(ws + 90177536);   // 2 MB  : v^T [8][64][2048]
  float* cosT  = (float*)(ws + 92274688);   // 256 KB
  float* sinT  = (float*)(ws + 92536832);   // 256 KB  (total ~88.5 MB)
  short* ab = xb;
  // GEMM2 partials reuse the dead qkvf region after prep (2 x 16 MB <= 48 MB)
  float* po0 = qkvfA;
  float* po1 = qkvfA + 4194304;
  (void)qkvfB; (void)ws_size;

  f2b5_kernel<<<14336, 256, 0, stream>>>(x, wq, wk, wv, wo,
                                         (unsigned short*)xb, (unsigned short*)wb,
                                         (unsigned short*)wob);
  trig_kernel<<<256, 256, 0, stream>>>(cosT, sinT);
  gemm_bt<<<dim3(24, 16, 2), 256, 0, stream>>>(xb, wb, qkvfA, 2048, 3072, 2048, 1024);
  prep_kernel<<<2048, 256, 0, stream>>>(qkvfA, qw, kw, cosT, sinT, qb, kb, vbt);
  attn_kernel<<<1024, 256, 0, stream>>>(qb, kb, vbt, ab);
  gemm_bt<<<dim3(16, 16, 2), 256, 0, stream>>>(ab, wob, po0, 2048, 2048, 2048, 1024);
  add2_kernel<<<2048, 256, 0, stream>>>(po0, po1, out);
}

// Round 12
// 156.026 us; speedup vs baseline: 1.2936x; 1.2936x over previous
//
#include <hip/hip_runtime.h>

typedef __attribute__((ext_vector_type(8))) short short8;
typedef __attribute__((ext_vector_type(4))) float f32x4;

#define MFMA_BF16 __builtin_amdgcn_mfma_f32_16x16x32_bf16

__device__ __forceinline__ unsigned short f2bf(float f) {
  unsigned u = __builtin_bit_cast(unsigned, f);
  u += 0x7fffu + ((u >> 16) & 1u);
  return (unsigned short)(u >> 16);
}

__device__ __forceinline__ unsigned cvtpk(float a, float b) {  // lo=bf16(a), hi=bf16(b)
  unsigned r;
  asm("v_cvt_pk_bf16_f32 %0, %1, %2" : "=v"(r) : "v"(a), "v"(b));
  return r;
}

__device__ __forceinline__ float b2f(short s) {
  return __builtin_bit_cast(float, ((unsigned)(unsigned short)s) << 16);
}

// ---------------- fused fp32 -> bf16 convert for all 5 inputs ----------------
__global__ __launch_bounds__(256) void f2b5_kernel(const float* __restrict__ x,
                                                   const float* __restrict__ wq,
                                                   const float* __restrict__ wk,
                                                   const float* __restrict__ wv,
                                                   const float* __restrict__ wo,
                                                   unsigned short* __restrict__ xb,
                                                   unsigned short* __restrict__ wb,
                                                   unsigned short* __restrict__ wob) {
  const int b = blockIdx.x;
  const float* src;
  unsigned short* dst;
  int base;
  if (b < 4096)      { src = x;  dst = xb;                base = b; }
  else if (b < 8192) { src = wq; dst = wb;                base = b - 4096; }
  else if (b < 9216) { src = wk; dst = wb + 2048 * 2048;  base = b - 8192; }
  else if (b < 10240){ src = wv; dst = wb + 2560 * 2048;  base = b - 9216; }
  else               { src = wo; dst = wob;               base = b - 10240; }
  const int i = base * 256 + threadIdx.x;
  const float4 v = ((const float4*)src)[i];
  ushort4 o = make_ushort4(f2bf(v.x), f2bf(v.y), f2bf(v.z), f2bf(v.w));
  ((ushort4*)dst)[i] = o;
}

// ---------------- RoPE trig table: [N][32] cos/sin (f64 once, tiny) ----------------
__global__ __launch_bounds__(256) void trig_kernel(float* __restrict__ cosT, float* __restrict__ sinT) {
  int i = blockIdx.x * 256 + threadIdx.x;  // [0, 2048*32)
  int n = i >> 5, f = i & 31;
  double ang = (double)n * pow(10000.0, -(double)f / 32.0);
  cosT[i] = (float)cos(ang);
  sinT[i] = (float)sin(ang);
}

// ---------------- split-K partial reduce: out = a + b (float4 x2 per thread) ----------------
__global__ __launch_bounds__(256) void add2_kernel(const float* __restrict__ a,
                                                   const float* __restrict__ b,
                                                   float* __restrict__ o) {
  int i = blockIdx.x * 256 + threadIdx.x;
#pragma unroll
  for (int s = 0; s < 2; ++s) {
    const float4 u = ((const float4*)a)[i], v = ((const float4*)b)[i];
    ((float4*)o)[i] = make_float4(u.x + v.x, u.y + v.y, u.z + v.z, u.w + v.w);
    i += 524288;
  }
}

// ---------------- bf16 NT GEMM, 2-phase double-buffered, split-K to partials ----------------
// C_z[M][N] = A[M][Kchunk_z] * B[N][Kchunk_z]^T ; z-slice writes C + z*M*N (plain stores).
// LDS chunk-XOR swizzle: LDS chunk c of row r holds global chunk c^(r&3)  (pre-swizzled src).
__global__ __launch_bounds__(256) void gemm_bt(const short* __restrict__ A,
                                               const short* __restrict__ B,
                                               float* __restrict__ C,
                                               int M, int N, int K, int KC) {
  __shared__ __align__(16) short As[2][128 * 32];
  __shared__ __align__(16) short Bs[2][128 * 32];
  const int tid = threadIdx.x;
  const int w = tid >> 6, lane = tid & 63;
  const int fr = lane & 15, fs = lane >> 4;
  const size_t brow = (size_t)blockIdx.y * 128, bcol = (size_t)blockIdx.x * 128;
  const int wr = (w >> 1) * 64, wc = (w & 1) * 64;
  const int lr = tid >> 2;          // staging row 0..63 (+64 for 2nd issue)
  const int lcS = ((tid & 3) ^ (lr & 3)) * 8;  // pre-swizzled source chunk (8 bf16 = 16B)
  const int ks = blockIdx.z * KC;
  C += (size_t)blockIdx.z * ((size_t)M * N);   // partial buffer for this z-slice
  const short* ga = A + (brow + lr) * (size_t)K + lcS + ks;
  const short* gb = B + (bcol + lr) * (size_t)K + lcS + ks;
  f32x4 acc[4][4] = {};

  auto stage = [&](int sb, int k0) {
    short* lA = As[sb] + w * 512;   // wave-uniform LDS dest (HW: base + lane*16B)
    short* lB = Bs[sb] + w * 512;
    __builtin_amdgcn_global_load_lds((__attribute__((address_space(1))) void*)(ga + k0),
                                     (__attribute__((address_space(3))) void*)(lA), 16, 0, 0);
    __builtin_amdgcn_global_load_lds((__attribute__((address_space(1))) void*)(ga + (size_t)64 * K + k0),
                                     (__attribute__((address_space(3))) void*)(lA + 2048), 16, 0, 0);
    __builtin_amdgcn_global_load_lds((__attribute__((address_space(1))) void*)(gb + k0),
                                     (__attribute__((address_space(3))) void*)(lB), 16, 0, 0);
    __builtin_amdgcn_global_load_lds((__attribute__((address_space(1))) void*)(gb + (size_t)64 * K + k0),
                                     (__attribute__((address_space(3))) void*)(lB + 2048), 16, 0, 0);
  };

  const int nk = KC >> 5;
  stage(0, 0);
  __syncthreads();                  // drain prologue loads
  int buf = 0;
  for (int t = 0; t < nk; ++t) {
    if (t + 1 < nk) stage(buf ^ 1, (t + 1) * 32);  // issue next-tile loads (in flight over MFMA)
    short8 af[4], bfr[4];
#pragma unroll
    for (int m = 0; m < 4; ++m)
      af[m] = *(const short8*)(As[buf] + (wr + m * 16 + fr) * 32 + ((fs ^ (fr & 3)) * 8));
#pragma unroll
    for (int n = 0; n < 4; ++n)
      bfr[n] = *(const short8*)(Bs[buf] + (wc + n * 16 + fr) * 32 + ((fs ^ (fr & 3)) * 8));
#pragma unroll
    for (int m = 0; m < 4; ++m)
#pragma unroll
      for (int n = 0; n < 4; ++n)
        acc[m][n] = MFMA_BF16(af[m], bfr[n], acc[m][n], 0, 0, 0);
    __syncthreads();                // vmcnt(0)+barrier: next tile staged, this buf free
    buf ^= 1;
  }
#pragma unroll
  for (int m = 0; m < 4; ++m)
#pragma unroll
    for (int n = 0; n < 4; ++n)
#pragma unroll
      for (int j = 0; j < 4; ++j)
        C[(brow + wr + m * 16 + fs * 4 + j) * (size_t)N + bcol + wc + n * 16 + fr] = acc[m][n][j];
}

// ---------------- fused split-K reduce + QK-RMSNorm + RoPE + head-major scatter ----------------
// qkv partials: qkvA/qkvB [N][3072] fp32 (q 0:2048 | k 2048:2560 | v 2560:3072); row = A + B
// qb: [H][N][64] bf16 (Q pre-scaled by D^-0.5 * log2e) ; kb: [KV][N][64] ; vbt: [KV][64][N]
__global__ __launch_bounds__(256) void prep_kernel(const float* __restrict__ qkv,
                                                   const float* __restrict__ qw,
                                                   const float* __restrict__ kw,
                                                   const float* __restrict__ cosT,
                                                   const float* __restrict__ sinT,
                                                   short* __restrict__ qb,
                                                   short* __restrict__ kb,
                                                   short* __restrict__ vbt) {
  const int n = blockIdx.x, t = threadIdx.x;
  const int w = t >> 6, lane = t & 63;
  __shared__ float redq[4], redk[4];
  const float* rowA = qkv + (size_t)n * 3072;
  const float* rowB = rowA + 6291456;  // second z-partial
  const float* cT = cosT + n * 32;
  const float* sT = sinT + n * 32;
  // --- Q: 2048 elems, 8/thread, norm over full 2048 ---
  const float4* r4a = (const float4*)rowA;
  const float4* r4b = (const float4*)rowB;
  float4 a0 = r4a[t * 2], a1 = r4b[t * 2];
  float4 b0 = r4a[t * 2 + 1], b1 = r4b[t * 2 + 1];
  float4 a = make_float4(a0.x + a1.x, a0.y + a1.y, a0.z + a1.z, a0.w + a1.w);
  float4 b = make_float4(b0.x + b1.x, b0.y + b1.y, b0.z + b1.z, b0.w + b1.w);
  float ss = a.x*a.x + a.y*a.y + a.z*a.z + a.w*a.w + b.x*b.x + b.y*b.y + b.z*b.z + b.w*b.w;
#pragma unroll
  for (int off = 32; off > 0; off >>= 1) ss += __shfl_xor(ss, off);
  if (lane == 0) redq[w] = ss;
  __syncthreads();
  // fold D^-0.5 and log2(e) (scores in log2-domain for exp2-based softmax)
  float rsq = rsqrtf((redq[0] + redq[1] + redq[2] + redq[3]) * (1.0f / 2048.f) + 1e-6f)
              * 0.125f * 1.44269504088896f;
  const int base = t * 8;
  float y[8] = {a.x, a.y, a.z, a.w, b.x, b.y, b.z, b.w};
#pragma unroll
  for (int e = 0; e < 8; ++e) y[e] *= rsq * qw[base + e];
  short8 ov;
  const int dbase = base & 63;
#pragma unroll
  for (int p = 0; p < 4; ++p) {
    float c = cT[(dbase >> 1) + p], s = sT[(dbase >> 1) + p];
    float x1 = y[2 * p], x2 = y[2 * p + 1];
    ov[2 * p]     = (short)f2bf(x1 * c - x2 * s);
    ov[2 * p + 1] = (short)f2bf(x1 * s + x2 * c);
  }
  const int h = base >> 6;
  *(short8*)(qb + ((size_t)h * 2048 + n) * 64 + dbase) = ov;
  // --- K: 512 elems, 2/thread, norm over full 512 ---
  const int ki = t * 2;
  float2 k0 = *(const float2*)(rowA + 2048 + ki);
  float2 k1 = *(const float2*)(rowB + 2048 + ki);
  float2 kv2 = make_float2(k0.x + k1.x, k0.y + k1.y);
  float ssk = kv2.x * kv2.x + kv2.y * kv2.y;
#pragma unroll
  for (int off = 32; off > 0; off >>= 1) ssk += __shfl_xor(ssk, off);
  if (lane == 0) redk[w] = ssk;
  __syncthreads();
  float rsk = rsqrtf((redk[0] + redk[1] + redk[2] + redk[3]) * (1.0f / 512.f) + 1e-6f);
  float z0 = kv2.x * rsk * kw[ki], z1 = kv2.y * rsk * kw[ki + 1];
  const int kd = ki & 63, kvh = ki >> 6;
  {
    float c = cT[kd >> 1], s = sT[kd >> 1];
    ushort2 o2 = make_ushort2(f2bf(z0 * c - z1 * s), f2bf(z0 * s + z1 * c));
    *(ushort2*)(kb + ((size_t)kvh * 2048 + n) * 64 + kd) = o2;
  }
  // --- V: bf16 + transpose store [KV][64][N] ---
  float2 v0 = *(const float2*)(rowA + 2560 + ki);
  float2 v1 = *(const float2*)(rowB + 2560 + ki);
  vbt[((size_t)kvh * 64 + kd) * 2048 + n]       = (short)f2bf(v0.x + v1.x);
  vbt[((size_t)kvh * 64 + kd + 1) * 2048 + n]   = (short)f2bf(v0.y + v1.y);
}

// ---------------- causal GQA flash attention v10: v7 body + split-KV ----------------
// 2048 blocks: (head, qblk, half). Each (h,qblk) split into two kv-ranges; each block
// writes UNNORMALIZED bf16 O-partial + (m,l) f32; merge_kernel combines.
// Critical path halves: 32 -> 16-17 tiles. Capacity 1024 (4 blocks/CU @ 40KB) -> backfill+LPT.
// Body identical to v7 (49.5us proven): K/V dbuf LDS staging, swapped MFMA(K,Q) softmax.
__global__ __launch_bounds__(256, 4) void attn_kernel(const short* __restrict__ qb,
                                                      const short* __restrict__ kb,
                                                      const short* __restrict__ vbt,
                                                      short* __restrict__ opart,
                                                      float2* __restrict__ mlb) {
  const int bid = blockIdx.x;
  const int h = bid & 31;
  const int idx = bid >> 5;               // 0..63
  const int qblk = 31 - (idx >> 1);       // longest first (LPT)
  const int half = idx & 1;
  const int kvh = h >> 2;                 // G=4
  const int tid = threadIdx.x;
  const int w = tid >> 6, lane = tid & 63;
  const int fr = lane & 15, fs = lane >> 4;
  const int q0w = qblk * 64 + w * 16;
  const int q_lane = q0w + fr;            // this lane's q row
  const int nt = qblk + 1;
  const int nh0 = (nt + 1) >> 1;
  const int tbeg = half ? nh0 : 0;
  const int tend = half ? nt : nh0;
  short* orow = opart + (size_t)half * 4194304 + ((size_t)h * 2048 + q_lane) * 64;
  if (tbeg >= tend) {                     // empty half (qblk==0, half==1)
    uint2 z = make_uint2(0u, 0u);
#pragma unroll
    for (int dt = 0; dt < 4; ++dt) *(uint2*)(orow + dt * 16 + fs * 4) = z;
    if (lane < 16) mlb[half * 65536 + h * 2048 + q_lane] = make_float2(-1e30f, 0.f);
    return;
  }
  __shared__ __align__(16) short Ks[2][64][64];  // [buf][kv][d], chunk c holds global chunk c^(kv&7)
  __shared__ __align__(16) short Vs[2][64][64];  // [buf][d][kv], chunk c holds global chunk c^(d&7)
  __shared__ __align__(16) short Ps[4][16][64];  // per-wave P[q][kv], u64-slot swizzled by (q&7)<<1
  const short* Kb = kb + (size_t)kvh * 2048 * 64;
  const short* Vb = vbt + (size_t)kvh * 64 * 2048;
  short8 qf[2];
  {
    const short* qrow = qb + ((size_t)h * 2048 + q_lane) * 64;
    qf[0] = *(const short8*)(qrow + fs * 8);
    qf[1] = *(const short8*)(qrow + 32 + fs * 8);
  }
  short8 ones8;
#pragma unroll
  for (int e = 0; e < 8; ++e) ones8[e] = (short)0x3F80;  // bf16 1.0
  f32x4 accO[4] = {};                     // O^T: lane q=fr, d = dt*16 + fs*4 + j
  f32x4 lacc = {};                        // row-sum via ones-MFMA
  float m = -1e30f;                       // scalar running max for this lane's q row
  short* prow = &Ps[w][fr][0];
  const int swz = (fr & 7) << 1;          // u64-slot XOR (bit0 free -> b128 reads contiguous)

  const int rS = lane >> 3;               // staging row within 8-row strip
  const int cS = (lane & 7) ^ rS;         // pre-swizzled source chunk
  auto stage = [&](int sb, int kv0s) {
#pragma unroll
    for (int i = 0; i < 2; ++i) {
      int r = i * 32 + w * 8 + rS;        // r & 7 == rS
      __builtin_amdgcn_global_load_lds(
          (__attribute__((address_space(1))) void*)(Kb + (size_t)(kv0s + r) * 64 + cS * 8),
          (__attribute__((address_space(3))) void*)(&Ks[sb][0][0] + i * 2048 + w * 512), 16, 0, 0);
      __builtin_amdgcn_global_load_lds(
          (__attribute__((address_space(1))) void*)(Vb + (size_t)r * 2048 + kv0s + cS * 8),
          (__attribute__((address_space(3))) void*)(&Vs[sb][0][0] + i * 2048 + w * 512), 16, 0, 0);
    }
  };

  int buf = 0;
  stage(0, tbeg * 64);
  __syncthreads();
  for (int t = tbeg; t < tend; ++t) {
    const int kv0 = t * 64;
    if (t + 1 < tend) stage(buf ^ 1, (t + 1) * 64);
    const short* KsB = &Ks[buf][0][0];
    const short* VsB = &Vs[buf][0][0];
    const int sw = (fr & 7);
    // ---- QK^T swapped: sc[ct][j] = S[kv=kv0+ct*16+fs*4+j][q=q_lane] (log2-domain) ----
    f32x4 sc[4];
#pragma unroll
    for (int ct = 0; ct < 4; ++ct) {
      const int rk = ct * 16 + fr;
      short8 kf0 = *(const short8*)(KsB + rk * 64 + ((fs ^ sw) * 8));
      short8 kf1 = *(const short8*)(KsB + rk * 64 + (((4 + fs) ^ sw) * 8));
      f32x4 a = {};
      a = MFMA_BF16(kf0, qf[0], a, 0, 0, 0);
      a = MFMA_BF16(kf1, qf[1], a, 0, 0, 0);
      sc[ct] = a;
    }
    // ---- causal mask (global diagonal tile only): kv > q ----
    if (t == qblk) {
#pragma unroll
      for (int ct = 0; ct < 4; ++ct) {
        const int kvb = kv0 + ct * 16 + fs * 4;
#pragma unroll
        for (int j = 0; j < 4; ++j)
          if (kvb + j > q_lane) sc[ct][j] = -1e30f;
      }
    }
    // ---- row max: 15 in-reg fmax + 2 shfl (lanes fr,fr+16,fr+32,fr+48 share q) ----
    float v0m = fmaxf(fmaxf(sc[0][0], sc[0][1]), fmaxf(sc[0][2], sc[0][3]));
    float v1m = fmaxf(fmaxf(sc[1][0], sc[1][1]), fmaxf(sc[1][2], sc[1][3]));
    float v2m = fmaxf(fmaxf(sc[2][0], sc[2][1]), fmaxf(sc[2][2], sc[2][3]));
    float v3m = fmaxf(fmaxf(sc[3][0], sc[3][1]), fmaxf(sc[3][2], sc[3][3]));
    float vmax = fmaxf(fmaxf(v0m, v1m), fmaxf(v2m, v3m));
    vmax = fmaxf(vmax, __shfl_xor(vmax, 16));
    vmax = fmaxf(vmax, __shfl_xor(vmax, 32));
    // ---- defer-max (T13, THR=8 in log2-domain -> P <= 256) ----
    if (!__all(vmax - m <= 8.0f)) {
      float mn = fmaxf(m, vmax);
      float resc = exp2f(m - mn);
      m = mn;
      lacc *= resc;
#pragma unroll
      for (int dt = 0; dt < 4; ++dt)
#pragma unroll
        for (int j = 0; j < 4; ++j) accO[dt][j] *= resc;
    }
    // ---- P = exp2(sc - m); cvt_pk pack; 4x swizzled ds_write_b64 ----
#pragma unroll
    for (int ct = 0; ct < 4; ++ct) {
      uint2 pk;
      pk.x = cvtpk(exp2f(sc[ct][0] - m), exp2f(sc[ct][1] - m));
      pk.y = cvtpk(exp2f(sc[ct][2] - m), exp2f(sc[ct][3] - m));
      *(uint2*)(prow + (((ct * 4 + fs) ^ swz) * 4)) = pk;
    }
    // ---- PV + row-sum: pa = B-frag of P^T (lane fr <-> q, elements fs*8+j <-> kv) ----
    short8 pa[2];
#pragma unroll
    for (int s = 0; s < 2; ++s)
      pa[s] = *(const short8*)(prow + (((s * 8 + fs * 2) ^ swz) * 4));
    __builtin_amdgcn_s_setprio(1);
    lacc = MFMA_BF16(ones8, pa[0], lacc, 0, 0, 0);
    lacc = MFMA_BF16(ones8, pa[1], lacc, 0, 0, 0);
#pragma unroll
    for (int dt = 0; dt < 4; ++dt) {
      const int rv = dt * 16 + fr;
      short8 vf0 = *(const short8*)(VsB + rv * 64 + ((fs ^ sw) * 8));
      short8 vf1 = *(const short8*)(VsB + rv * 64 + (((4 + fs) ^ sw) * 8));
      accO[dt] = MFMA_BF16(vf0, pa[0], accO[dt], 0, 0, 0);
      accO[dt] = MFMA_BF16(vf1, pa[1], accO[dt], 0, 0, 0);
    }
    __builtin_amdgcn_s_setprio(0);
    __syncthreads();
    buf ^= 1;
  }
  // ---- epilogue: UNNORMALIZED O-partial (bf16) + (m, l) f32 ----
#pragma unroll
  for (int dt = 0; dt < 4; ++dt) {
    uint2 o;
    o.x = cvtpk(accO[dt][0], accO[dt][1]);
    o.y = cvtpk(accO[dt][2], accO[dt][3]);
    *(uint2*)(orow + dt * 16 + fs * 4) = o;
  }
  if (lane < 16) mlb[half * 65536 + h * 2048 + q_lane] = make_float2(m, lacc[0]);
}

// ---------------- split-KV merge: O = (O0*2^(m0-m) + O1*2^(m1-m)) / l ----------------
// thread -> (h, q, 8-elem d-chunk); 2048 blocks x 256
__global__ __launch_bounds__(256) void merge_kernel(const short* __restrict__ opart,
                                                    const float2* __restrict__ mlb,
                                                    short* __restrict__ ab) {
  const int gid = blockIdx.x * 256 + threadIdx.x;
  const int dc = gid & 7;
  const int q = (gid >> 3) & 2047;
  const int h = gid >> 14;
  const int hq = h * 2048 + q;
  const float2 ml0 = mlb[hq], ml1 = mlb[65536 + hq];
  const float mm = fmaxf(ml0.x, ml1.x);
  const float s0 = exp2f(ml0.x - mm), s1 = exp2f(ml1.x - mm);
  const float inv = 1.0f / (ml0.y * s0 + ml1.y * s1);
  const size_t b0 = (size_t)hq * 64 + dc * 8;
  const short8 o0 = *(const short8*)(opart + b0);
  const short8 o1 = *(const short8*)(opart + b0 + 4194304);
  short8 o;
#pragma unroll
  for (int j = 0; j < 8; ++j)
    o[j] = (short)f2bf((b2f(o0[j]) * s0 + b2f(o1[j]) * s1) * inv);
  *(short8*)(ab + (size_t)q * 2048 + h * 64 + dc * 8) = o;
}

extern "C" void kernel_launch(void* const* d_in, const int* in_sizes, int n_in,
                              void* d_out, int out_size, void* d_ws, size_t ws_size,
                              hipStream_t stream) {
  const float* x  = (const float*)d_in[0];
  const float* wq = (const float*)d_in[1];
  const float* wk = (const float*)d_in[2];
  const float* wv = (const float*)d_in[3];
  const float* wo = (const float*)d_in[4];
  const float* qw = (const float*)d_in[5];
  const float* kw = (const float*)d_in[6];
  float* out = (float*)d_out;
  char* ws = (char*)d_ws;
  short* xb    = (short*)(ws + 0);          // 8 MB  : x bf16, then attn-out bf16
  short* wb    = (short*)(ws + 8388608);    // 12 MB : [wq;wk;wv] bf16 (dead after gemm1 -> mlb)
  short* wob   = (short*)(ws + 20971520);   // 8 MB  : wo bf16
  float* qkvfA = (float*)(ws + 29360128);   // 24 MB : qkv z0 partial [2048][3072] f32
  float* qkvfB = (float*)(ws + 54525952);   // 24 MB : qkv z1 partial (dead after prep)
  short* qb    = (short*)(ws + 79691776);   // 8 MB  : q roped+scaled [32][2048][64]
  short* kb    = (short*)(ws + 88080384);   // 2 MB  : k roped [8][2048][64]
  short* vbt   = (short*)(ws + 90177536);   // 2 MB  : v^T [8][64][2048]
  float* cosT  = (float*)(ws + 92274688);   // 256 KB
  float* sinT  = (float*)(ws + 92536832);   // 256 KB  (total ~88.5 MB)
  short* ab = xb;
  // dead-region reuse after prep/gemm1:
  float* po0 = qkvfA;                       // gemm2 z0 partial (16 MB)
  float* po1 = qkvfA + 4194304;             // gemm2 z1 partial (16 MB, spills into qkvfB head)
  short* opart = (short*)(ws + 62914560);   // 16.8 MB O-partials [2][32][2048][64] bf16 (qkvfB tail)
  float2* mlb  = (float2*)(ws + 8388608);   // 1 MB (m,l) [2][32][2048] (dead wb region)
  (void)qkvfB; (void)ws_size;

  f2b5_kernel<<<14336, 256, 0, stream>>>(x, wq, wk, wv, wo,
                                         (unsigned short*)xb, (unsigned short*)wb,
                                         (unsigned short*)wob);
  trig_kernel<<<256, 256, 0, stream>>>(cosT, sinT);
  gemm_bt<<<dim3(24, 16, 2), 256, 0, stream>>>(xb, wb, qkvfA, 2048, 3072, 2048, 1024);
  prep_kernel<<<2048, 256, 0, stream>>>(qkvfA, qw, kw, cosT, sinT, qb, kb, vbt);
  attn_kernel<<<2048, 256, 0, stream>>>(qb, kb, vbt, opart, mlb);
  merge_kernel<<<2048, 256, 0, stream>>>(opart, mlb, ab);
  gemm_bt<<<dim3(16, 16, 2), 256, 0, stream>>>(ab, wob, po0, 2048, 2048, 2048, 1024);
  add2_kernel<<<2048, 256, 0, stream>>>(po0, po1, out);
}

// Round 13
// 152.871 us; speedup vs baseline: 1.3203x; 1.0206x over previous
//
#include <hip/hip_runtime.h>

typedef __attribute__((ext_vector_type(8))) short short8;
typedef __attribute__((ext_vector_type(4))) float f32x4;

#define MFMA_BF16 __builtin_amdgcn_mfma_f32_16x16x32_bf16

__device__ __forceinline__ unsigned short f2bf(float f) {
  unsigned u = __builtin_bit_cast(unsigned, f);
  u += 0x7fffu + ((u >> 16) & 1u);
  return (unsigned short)(u >> 16);
}

__device__ __forceinline__ unsigned cvtpk(float a, float b) {  // lo=bf16(a), hi=bf16(b)
  unsigned r;
  asm("v_cvt_pk_bf16_f32 %0, %1, %2" : "=v"(r) : "v"(a), "v"(b));
  return r;
}

// ---------------- fused fp32 -> bf16 convert for all 5 inputs ----------------
__global__ __launch_bounds__(256) void f2b5_kernel(const float* __restrict__ x,
                                                   const float* __restrict__ wq,
                                                   const float* __restrict__ wk,
                                                   const float* __restrict__ wv,
                                                   const float* __restrict__ wo,
                                                   unsigned short* __restrict__ xb,
                                                   unsigned short* __restrict__ wb,
                                                   unsigned short* __restrict__ wob) {
  const int b = blockIdx.x;
  const float* src;
  unsigned short* dst;
  int base;
  if (b < 4096)      { src = x;  dst = xb;                base = b; }
  else if (b < 8192) { src = wq; dst = wb;                base = b - 4096; }
  else if (b < 9216) { src = wk; dst = wb + 2048 * 2048;  base = b - 8192; }
  else if (b < 10240){ src = wv; dst = wb + 2560 * 2048;  base = b - 9216; }
  else               { src = wo; dst = wob;               base = b - 10240; }
  const int i = base * 256 + threadIdx.x;
  const float4 v = ((const float4*)src)[i];
  ushort4 o = make_ushort4(f2bf(v.x), f2bf(v.y), f2bf(v.z), f2bf(v.w));
  ((ushort4*)dst)[i] = o;
}

// ---------------- RoPE trig table: [N][32] cos/sin (f64 once, tiny) ----------------
__global__ __launch_bounds__(256) void trig_kernel(float* __restrict__ cosT, float* __restrict__ sinT) {
  int i = blockIdx.x * 256 + threadIdx.x;  // [0, 2048*32)
  int n = i >> 5, f = i & 31;
  double ang = (double)n * pow(10000.0, -(double)f / 32.0);
  cosT[i] = (float)cos(ang);
  sinT[i] = (float)sin(ang);
}

// ---------------- bf16 NT GEMM, 2-phase double-buffered, tile 128 x BN ----------------
// C_z[M][N] = A[M][Kchunk_z] * B[N][Kchunk_z]^T ; z-slice writes C + z*M*N (plain stores).
// BN=128: 4 waves each 64x64 (acc 4x4). BN=64: 4 waves each 64x32 (acc 4x2), direct-write path.
// LDS chunk-XOR swizzle: LDS chunk c of row r holds global chunk c^(r&3) (pre-swizzled src).
template <int BN>
__global__ __launch_bounds__(256) void gemm_bt(const short* __restrict__ A,
                                               const short* __restrict__ B,
                                               float* __restrict__ C,
                                               int M, int N, int K, int KC) {
  __shared__ __align__(16) short As[2][128 * 32];
  __shared__ __align__(16) short Bs[2][BN * 32];
  const int tid = threadIdx.x;
  const int w = tid >> 6, lane = tid & 63;
  const int fr = lane & 15, fs = lane >> 4;
  const size_t brow = (size_t)blockIdx.y * 128, bcol = (size_t)blockIdx.x * BN;
  const int wr = (w >> 1) * 64, wc = (w & 1) * (BN / 2);
  const int lr = tid >> 2;          // staging row 0..63 (+64 for 2nd issue)
  const int lcS = ((tid & 3) ^ (lr & 3)) * 8;  // pre-swizzled source chunk (8 bf16 = 16B)
  const int ks = blockIdx.z * KC;
  C += (size_t)blockIdx.z * ((size_t)M * N);   // partial buffer for this z-slice
  const short* ga = A + (brow + lr) * (size_t)K + lcS + ks;
  const short* gb = B + (bcol + lr) * (size_t)K + lcS + ks;
  f32x4 acc[4][BN / 32] = {};

  auto stage = [&](int sb, int k0) {
    short* lA = As[sb] + w * 512;   // wave-uniform LDS dest (HW: base + lane*16B)
    short* lB = Bs[sb] + w * 512;
    __builtin_amdgcn_global_load_lds((__attribute__((address_space(1))) void*)(ga + k0),
                                     (__attribute__((address_space(3))) void*)(lA), 16, 0, 0);
    __builtin_amdgcn_global_load_lds((__attribute__((address_space(1))) void*)(ga + (size_t)64 * K + k0),
                                     (__attribute__((address_space(3))) void*)(lA + 2048), 16, 0, 0);
    __builtin_amdgcn_global_load_lds((__attribute__((address_space(1))) void*)(gb + k0),
                                     (__attribute__((address_space(3))) void*)(lB), 16, 0, 0);
    if (BN == 128)
      __builtin_amdgcn_global_load_lds((__attribute__((address_space(1))) void*)(gb + (size_t)64 * K + k0),
                                       (__attribute__((address_space(3))) void*)(lB + 2048), 16, 0, 0);
  };

  const int nk = KC >> 5;
  stage(0, 0);
  __syncthreads();                  // drain prologue loads
  int buf = 0;
  for (int t = 0; t < nk; ++t) {
    if (t + 1 < nk) stage(buf ^ 1, (t + 1) * 32);  // issue next-tile loads (in flight over MFMA)
    short8 af[4], bfr[BN / 32];
#pragma unroll
    for (int m = 0; m < 4; ++m)
      af[m] = *(const short8*)(As[buf] + (wr + m * 16 + fr) * 32 + ((fs ^ (fr & 3)) * 8));
#pragma unroll
    for (int n = 0; n < BN / 32; ++n)
      bfr[n] = *(const short8*)(Bs[buf] + (wc + n * 16 + fr) * 32 + ((fs ^ (fr & 3)) * 8));
#pragma unroll
    for (int m = 0; m < 4; ++m)
#pragma unroll
      for (int n = 0; n < BN / 32; ++n)
        acc[m][n] = MFMA_BF16(af[m], bfr[n], acc[m][n], 0, 0, 0);
    __syncthreads();                // vmcnt(0)+barrier: next tile staged, this buf free
    buf ^= 1;
  }
#pragma unroll
  for (int m = 0; m < 4; ++m)
#pragma unroll
    for (int n = 0; n < BN / 32; ++n)
#pragma unroll
      for (int j = 0; j < 4; ++j)
        C[(brow + wr + m * 16 + fs * 4 + j) * (size_t)N + bcol + wc + n * 16 + fr] = acc[m][n][j];
}

// ---------------- fused split-K reduce + QK-RMSNorm + RoPE + head-major scatter ----------------
// qkv partials: qkvA/qkvB [N][3072] fp32 (q 0:2048 | k 2048:2560 | v 2560:3072); row = A + B
// qb: [H][N][64] bf16 (Q pre-scaled by D^-0.5 * log2e) ; kb: [KV][N][64] ; vbt: [KV][64][N]
__global__ __launch_bounds__(256) void prep_kernel(const float* __restrict__ qkv,
                                                   const float* __restrict__ qw,
                                                   const float* __restrict__ kw,
                                                   const float* __restrict__ cosT,
                                                   const float* __restrict__ sinT,
                                                   short* __restrict__ qb,
                                                   short* __restrict__ kb,
                                                   short* __restrict__ vbt) {
  const int n = blockIdx.x, t = threadIdx.x;
  const int w = t >> 6, lane = t & 63;
  __shared__ float redq[4], redk[4];
  const float* rowA = qkv + (size_t)n * 3072;
  const float* rowB = rowA + 6291456;  // second z-partial
  const float* cT = cosT + n * 32;
  const float* sT = sinT + n * 32;
  // --- Q: 2048 elems, 8/thread, norm over full 2048 ---
  const float4* r4a = (const float4*)rowA;
  const float4* r4b = (const float4*)rowB;
  float4 a0 = r4a[t * 2], a1 = r4b[t * 2];
  float4 b0 = r4a[t * 2 + 1], b1 = r4b[t * 2 + 1];
  float4 a = make_float4(a0.x + a1.x, a0.y + a1.y, a0.z + a1.z, a0.w + a1.w);
  float4 b = make_float4(b0.x + b1.x, b0.y + b1.y, b0.z + b1.z, b0.w + b1.w);
  float ss = a.x*a.x + a.y*a.y + a.z*a.z + a.w*a.w + b.x*b.x + b.y*b.y + b.z*b.z + b.w*b.w;
#pragma unroll
  for (int off = 32; off > 0; off >>= 1) ss += __shfl_xor(ss, off);
  if (lane == 0) redq[w] = ss;
  __syncthreads();
  // fold D^-0.5 and log2(e) (scores in log2-domain for exp2-based softmax)
  float rsq = rsqrtf((redq[0] + redq[1] + redq[2] + redq[3]) * (1.0f / 2048.f) + 1e-6f)
              * 0.125f * 1.44269504088896f;
  const int base = t * 8;
  float y[8] = {a.x, a.y, a.z, a.w, b.x, b.y, b.z, b.w};
#pragma unroll
  for (int e = 0; e < 8; ++e) y[e] *= rsq * qw[base + e];
  short8 ov;
  const int dbase = base & 63;
#pragma unroll
  for (int p = 0; p < 4; ++p) {
    float c = cT[(dbase >> 1) + p], s = sT[(dbase >> 1) + p];
    float x1 = y[2 * p], x2 = y[2 * p + 1];
    ov[2 * p]     = (short)f2bf(x1 * c - x2 * s);
    ov[2 * p + 1] = (short)f2bf(x1 * s + x2 * c);
  }
  const int h = base >> 6;
  *(short8*)(qb + ((size_t)h * 2048 + n) * 64 + dbase) = ov;
  // --- K: 512 elems, 2/thread, norm over full 512 ---
  const int ki = t * 2;
  float2 k0 = *(const float2*)(rowA + 2048 + ki);
  float2 k1 = *(const float2*)(rowB + 2048 + ki);
  float2 kv2 = make_float2(k0.x + k1.x, k0.y + k1.y);
  float ssk = kv2.x * kv2.x + kv2.y * kv2.y;
#pragma unroll
  for (int off = 32; off > 0; off >>= 1) ssk += __shfl_xor(ssk, off);
  if (lane == 0) redk[w] = ssk;
  __syncthreads();
  float rsk = rsqrtf((redk[0] + redk[1] + redk[2] + redk[3]) * (1.0f / 512.f) + 1e-6f);
  float z0 = kv2.x * rsk * kw[ki], z1 = kv2.y * rsk * kw[ki + 1];
  const int kd = ki & 63, kvh = ki >> 6;
  {
    float c = cT[kd >> 1], s = sT[kd >> 1];
    ushort2 o2 = make_ushort2(f2bf(z0 * c - z1 * s), f2bf(z0 * s + z1 * c));
    *(ushort2*)(kb + ((size_t)kvh * 2048 + n) * 64 + kd) = o2;
  }
  // --- V: bf16 + transpose store [KV][64][N] ---
  float2 v0 = *(const float2*)(rowA + 2560 + ki);
  float2 v1 = *(const float2*)(rowB + 2560 + ki);
  vbt[((size_t)kvh * 64 + kd) * 2048 + n]       = (short)f2bf(v0.x + v1.x);
  vbt[((size_t)kvh * 64 + kd + 1) * 2048 + n]   = (short)f2bf(v0.y + v1.y);
}

// ---------------- causal GQA flash attention v7 (proven 49.5us) ----------------
// 1024 blocks (head, qblk) longest-first; 4 waves * 16 q-rows; KVBLK=64; LDS 40KB -> 4 blocks/CU.
// K/V double-buffered in LDS (global_load_lds w=16, pre-swizzled src).
// Swapped MFMA(K,Q): lane owns ONE q-row -> scalar m/l, 2-shfl max, cvt_pk P-pack,
// 4x ds_write_b64, O^T epilogue.
__global__ __launch_bounds__(256, 4) void attn_kernel(const short* __restrict__ qb,
                                                      const short* __restrict__ kb,
                                                      const short* __restrict__ vbt,
                                                      short* __restrict__ ab) {
  const int bid = blockIdx.x;
  const int h = bid & 31;
  const int qblk = 31 - (bid >> 5);       // longest blocks dispatch first
  const int kvh = h >> 2;                 // G=4
  const int tid = threadIdx.x;
  const int w = tid >> 6, lane = tid & 63;
  const int fr = lane & 15, fs = lane >> 4;
  const int q0w = qblk * 64 + w * 16;
  const int q_lane = q0w + fr;            // this lane's q row
  __shared__ __align__(16) short Ks[2][64][64];  // [buf][kv][d], chunk c holds global chunk c^(kv&7)
  __shared__ __align__(16) short Vs[2][64][64];  // [buf][d][kv], chunk c holds global chunk c^(d&7)
  __shared__ __align__(16) short Ps[4][16][64];  // per-wave P[q][kv], u64-slot swizzled by (q&7)<<1
  const short* Kb = kb + (size_t)kvh * 2048 * 64;
  const short* Vb = vbt + (size_t)kvh * 64 * 2048;
  short8 qf[2];
  {
    const short* qrow = qb + ((size_t)h * 2048 + q_lane) * 64;
    qf[0] = *(const short8*)(qrow + fs * 8);
    qf[1] = *(const short8*)(qrow + 32 + fs * 8);
  }
  short8 ones8;
#pragma unroll
  for (int e = 0; e < 8; ++e) ones8[e] = (short)0x3F80;  // bf16 1.0
  f32x4 accO[4] = {};                     // O^T: lane q=fr, d = dt*16 + fs*4 + j
  f32x4 lacc = {};                        // row-sum via ones-MFMA (all regs equal)
  float m = -1e30f;                       // scalar running max for this lane's q row
  short* prow = &Ps[w][fr][0];
  const int swz = (fr & 7) << 1;          // u64-slot XOR (bit0 free -> b128 reads contiguous)

  const int rS = lane >> 3;               // staging row within 8-row strip
  const int cS = (lane & 7) ^ rS;         // pre-swizzled source chunk
  auto stage = [&](int sb, int kv0s) {
#pragma unroll
    for (int i = 0; i < 2; ++i) {
      int r = i * 32 + w * 8 + rS;        // r & 7 == rS
      __builtin_amdgcn_global_load_lds(
          (__attribute__((address_space(1))) void*)(Kb + (size_t)(kv0s + r) * 64 + cS * 8),
          (__attribute__((address_space(3))) void*)(&Ks[sb][0][0] + i * 2048 + w * 512), 16, 0, 0);
      __builtin_amdgcn_global_load_lds(
          (__attribute__((address_space(1))) void*)(Vb + (size_t)r * 2048 + kv0s + cS * 8),
          (__attribute__((address_space(3))) void*)(&Vs[sb][0][0] + i * 2048 + w * 512), 16, 0, 0);
    }
  };

  const int ntiles = qblk + 1;
  int buf = 0;
  stage(0, 0);
  __syncthreads();
  for (int t = 0; t < ntiles; ++t) {
    const int kv0 = t * 64;
    if (t + 1 < ntiles) stage(buf ^ 1, (t + 1) * 64);
    const short* KsB = &Ks[buf][0][0];
    const short* VsB = &Vs[buf][0][0];
    const int sw = (fr & 7);
    // ---- QK^T swapped: sc[ct][j] = S[kv=kv0+ct*16+fs*4+j][q=q_lane] (log2-domain) ----
    f32x4 sc[4];
#pragma unroll
    for (int ct = 0; ct < 4; ++ct) {
      const int rk = ct * 16 + fr;
      short8 kf0 = *(const short8*)(KsB + rk * 64 + ((fs ^ sw) * 8));
      short8 kf1 = *(const short8*)(KsB + rk * 64 + (((4 + fs) ^ sw) * 8));
      f32x4 a = {};
      a = MFMA_BF16(kf0, qf[0], a, 0, 0, 0);
      a = MFMA_BF16(kf1, qf[1], a, 0, 0, 0);
      sc[ct] = a;
    }
    // ---- causal mask (diagonal tile only): kv > q ----
    if (t == qblk) {
#pragma unroll
      for (int ct = 0; ct < 4; ++ct) {
        const int kvb = kv0 + ct * 16 + fs * 4;
#pragma unroll
        for (int j = 0; j < 4; ++j)
          if (kvb + j > q_lane) sc[ct][j] = -1e30f;
      }
    }
    // ---- row max: 15 in-reg fmax + 2 shfl (lanes fr,fr+16,fr+32,fr+48 share q) ----
    float v0m = fmaxf(fmaxf(sc[0][0], sc[0][1]), fmaxf(sc[0][2], sc[0][3]));
    float v1m = fmaxf(fmaxf(sc[1][0], sc[1][1]), fmaxf(sc[1][2], sc[1][3]));
    float v2m = fmaxf(fmaxf(sc[2][0], sc[2][1]), fmaxf(sc[2][2], sc[2][3]));
    float v3m = fmaxf(fmaxf(sc[3][0], sc[3][1]), fmaxf(sc[3][2], sc[3][3]));
    float vmax = fmaxf(fmaxf(v0m, v1m), fmaxf(v2m, v3m));
    vmax = fmaxf(vmax, __shfl_xor(vmax, 16));
    vmax = fmaxf(vmax, __shfl_xor(vmax, 32));
    // ---- defer-max (T13, THR=8 in log2-domain -> P <= 256) ----
    if (!__all(vmax - m <= 8.0f)) {
      float mn = fmaxf(m, vmax);
      float resc = exp2f(m - mn);
      m = mn;
      lacc *= resc;
#pragma unroll
      for (int dt = 0; dt < 4; ++dt)
#pragma unroll
        for (int j = 0; j < 4; ++j) accO[dt][j] *= resc;
    }
    // ---- P = exp2(sc - m); cvt_pk pack; 4x swizzled ds_write_b64 ----
#pragma unroll
    for (int ct = 0; ct < 4; ++ct) {
      uint2 pk;
      pk.x = cvtpk(exp2f(sc[ct][0] - m), exp2f(sc[ct][1] - m));
      pk.y = cvtpk(exp2f(sc[ct][2] - m), exp2f(sc[ct][3] - m));
      *(uint2*)(prow + (((ct * 4 + fs) ^ swz) * 4)) = pk;
    }
    // ---- PV + row-sum: pa = B-frag of P^T (lane fr <-> q, elements fs*8+j <-> kv) ----
    short8 pa[2];
#pragma unroll
    for (int s = 0; s < 2; ++s)
      pa[s] = *(const short8*)(prow + (((s * 8 + fs * 2) ^ swz) * 4));
    __builtin_amdgcn_s_setprio(1);
    lacc = MFMA_BF16(ones8, pa[0], lacc, 0, 0, 0);
    lacc = MFMA_BF16(ones8, pa[1], lacc, 0, 0, 0);
#pragma unroll
    for (int dt = 0; dt < 4; ++dt) {
      const int rv = dt * 16 + fr;
      short8 vf0 = *(const short8*)(VsB + rv * 64 + ((fs ^ sw) * 8));
      short8 vf1 = *(const short8*)(VsB + rv * 64 + (((4 + fs) ^ sw) * 8));
      accO[dt] = MFMA_BF16(vf0, pa[0], accO[dt], 0, 0, 0);
      accO[dt] = MFMA_BF16(vf1, pa[1], accO[dt], 0, 0, 0);
    }
    __builtin_amdgcn_s_setprio(0);
    __syncthreads();
    buf ^= 1;
  }
  // ---- epilogue: O = O^T normalized; packed 8B stores ----
  const float inv = 1.0f / lacc[0];
  short* orow = ab + (size_t)q_lane * 2048 + h * 64;
#pragma unroll
  for (int dt = 0; dt < 4; ++dt) {
    uint2 o;
    o.x = cvtpk(accO[dt][0] * inv, accO[dt][1] * inv);
    o.y = cvtpk(accO[dt][2] * inv, accO[dt][3] * inv);
    *(uint2*)(orow + dt * 16 + fs * 4) = o;
  }
}

extern "C" void kernel_launch(void* const* d_in, const int* in_sizes, int n_in,
                              void* d_out, int out_size, void* d_ws, size_t ws_size,
                              hipStream_t stream) {
  const float* x  = (const float*)d_in[0];
  const float* wq = (const float*)d_in[1];
  const float* wk = (const float*)d_in[2];
  const float* wv = (const float*)d_in[3];
  const float* wo = (const float*)d_in[4];
  const float* qw = (const float*)d_in[5];
  const float* kw = (const float*)d_in[6];
  float* out = (float*)d_out;
  char* ws = (char*)d_ws;
  short* xb    = (short*)(ws + 0);          // 8 MB  : x bf16, then attn-out bf16
  short* wb    = (short*)(ws + 8388608);    // 12 MB : [wq;wk;wv] bf16 [3072][2048]
  short* wob   = (short*)(ws + 20971520);   // 8 MB  : wo bf16
  float* qkvfA = (float*)(ws + 29360128);   // 24 MB : qkv z0 partial [2048][3072] f32
  float* qkvfB = (float*)(ws + 54525952);   // 24 MB : qkv z1 partial (contiguous after A)
  short* qb    = (short*)(ws + 79691776);   // 8 MB  : q roped+scaled [32][2048][64]
  short* kb    = (short*)(ws + 88080384);   // 2 MB  : k roped [8][2048][64]
  short* vbt   = (short*)(ws + 90177536);   // 2 MB  : v^T [8][64][2048]
  float* cosT  = (float*)(ws + 92274688);   // 256 KB
  float* sinT  = (float*)(ws + 92536832);   // 256 KB  (total ~88.5 MB)
  short* ab = xb;
  (void)qkvfB; (void)ws_size;

  f2b5_kernel<<<14336, 256, 0, stream>>>(x, wq, wk, wv, wo,
                                         (unsigned short*)xb, (unsigned short*)wb,
                                         (unsigned short*)wob);
  trig_kernel<<<256, 256, 0, stream>>>(cosT, sinT);
  gemm_bt<128><<<dim3(24, 16, 2), 256, 0, stream>>>(xb, wb, qkvfA, 2048, 3072, 2048, 1024);
  prep_kernel<<<2048, 256, 0, stream>>>(qkvfA, qw, kw, cosT, sinT, qb, kb, vbt);
  attn_kernel<<<1024, 256, 0, stream>>>(qb, kb, vbt, ab);
  gemm_bt<64><<<dim3(32, 16, 1), 256, 0, stream>>>(ab, wob, out, 2048, 2048, 2048, 2048);
}

// Round 14
// 143.819 us; speedup vs baseline: 1.4034x; 1.0629x over previous
//
#include <hip/hip_runtime.h>

typedef __attribute__((ext_vector_type(8))) short short8;
typedef __attribute__((ext_vector_type(4))) float f32x4;

#define MFMA_BF16 __builtin_amdgcn_mfma_f32_16x16x32_bf16

__device__ __forceinline__ unsigned short f2bf(float f) {
  unsigned u = __builtin_bit_cast(unsigned, f);
  u += 0x7fffu + ((u >> 16) & 1u);
  return (unsigned short)(u >> 16);
}

__device__ __forceinline__ unsigned cvtpk(float a, float b) {  // lo=bf16(a), hi=bf16(b)
  unsigned r;
  asm("v_cvt_pk_bf16_f32 %0, %1, %2" : "=v"(r) : "v"(a), "v"(b));
  return r;
}

// ---------------- fused fp32 -> bf16 convert for all 5 inputs ----------------
__global__ __launch_bounds__(256) void f2b5_kernel(const float* __restrict__ x,
                                                   const float* __restrict__ wq,
                                                   const float* __restrict__ wk,
                                                   const float* __restrict__ wv,
                                                   const float* __restrict__ wo,
                                                   unsigned short* __restrict__ xb,
                                                   unsigned short* __restrict__ wb,
                                                   unsigned short* __restrict__ wob) {
  const int b = blockIdx.x;
  const float* src;
  unsigned short* dst;
  int base;
  if (b < 4096)      { src = x;  dst = xb;                base = b; }
  else if (b < 8192) { src = wq; dst = wb;                base = b - 4096; }
  else if (b < 9216) { src = wk; dst = wb + 2048 * 2048;  base = b - 8192; }
  else if (b < 10240){ src = wv; dst = wb + 2560 * 2048;  base = b - 9216; }
  else               { src = wo; dst = wob;               base = b - 10240; }
  const int i = base * 256 + threadIdx.x;
  const float4 v = ((const float4*)src)[i];
  ushort4 o = make_ushort4(f2bf(v.x), f2bf(v.y), f2bf(v.z), f2bf(v.w));
  ((ushort4*)dst)[i] = o;
}

// ---------------- RoPE trig table: [N][32] cos/sin (f64 once, tiny) ----------------
__global__ __launch_bounds__(256) void trig_kernel(float* __restrict__ cosT, float* __restrict__ sinT) {
  int i = blockIdx.x * 256 + threadIdx.x;  // [0, 2048*32)
  int n = i >> 5, f = i & 31;
  double ang = (double)n * pow(10000.0, -(double)f / 32.0);
  cosT[i] = (float)cos(ang);
  sinT[i] = (float)sin(ang);
}

// ---------------- bf16 NT GEMM, 2-phase double-buffered, tile 128 x BN ----------------
// C_z[M][N] = A[M][Kchunk_z] * B[N][Kchunk_z]^T ; z-slice writes C + z*M*N (plain stores).
// BN=128: 4 waves each 64x64 (acc 4x4). BN=64: 4 waves each 64x32 (acc 4x2), direct-write path.
// LDS chunk-XOR swizzle: LDS chunk c of row r holds global chunk c^(r&3) (pre-swizzled src).
template <int BN>
__global__ __launch_bounds__(256) void gemm_bt(const short* __restrict__ A,
                                               const short* __restrict__ B,
                                               float* __restrict__ C,
                                               int M, int N, int K, int KC) {
  __shared__ __align__(16) short As[2][128 * 32];
  __shared__ __align__(16) short Bs[2][BN * 32];
  const int tid = threadIdx.x;
  const int w = tid >> 6, lane = tid & 63;
  const int fr = lane & 15, fs = lane >> 4;
  const size_t brow = (size_t)blockIdx.y * 128, bcol = (size_t)blockIdx.x * BN;
  const int wr = (w >> 1) * 64, wc = (w & 1) * (BN / 2);
  const int lr = tid >> 2;          // staging row 0..63 (+64 for 2nd issue)
  const int lcS = ((tid & 3) ^ (lr & 3)) * 8;  // pre-swizzled source chunk (8 bf16 = 16B)
  const int ks = blockIdx.z * KC;
  C += (size_t)blockIdx.z * ((size_t)M * N);   // partial buffer for this z-slice
  const short* ga = A + (brow + lr) * (size_t)K + lcS + ks;
  const short* gb = B + (bcol + lr) * (size_t)K + lcS + ks;
  f32x4 acc[4][BN / 32] = {};

  auto stage = [&](int sb, int k0) {
    short* lA = As[sb] + w * 512;   // wave-uniform LDS dest (HW: base + lane*16B)
    short* lB = Bs[sb] + w * 512;
    __builtin_amdgcn_global_load_lds((__attribute__((address_space(1))) void*)(ga + k0),
                                     (__attribute__((address_space(3))) void*)(lA), 16, 0, 0);
    __builtin_amdgcn_global_load_lds((__attribute__((address_space(1))) void*)(ga + (size_t)64 * K + k0),
                                     (__attribute__((address_space(3))) void*)(lA + 2048), 16, 0, 0);
    __builtin_amdgcn_global_load_lds((__attribute__((address_space(1))) void*)(gb + k0),
                                     (__attribute__((address_space(3))) void*)(lB), 16, 0, 0);
    if (BN == 128)
      __builtin_amdgcn_global_load_lds((__attribute__((address_space(1))) void*)(gb + (size_t)64 * K + k0),
                                       (__attribute__((address_space(3))) void*)(lB + 2048), 16, 0, 0);
  };

  const int nk = KC >> 5;
  stage(0, 0);
  __syncthreads();                  // drain prologue loads
  int buf = 0;
  for (int t = 0; t < nk; ++t) {
    if (t + 1 < nk) stage(buf ^ 1, (t + 1) * 32);  // issue next-tile loads (in flight over MFMA)
    short8 af[4], bfr[BN / 32];
#pragma unroll
    for (int m = 0; m < 4; ++m)
      af[m] = *(const short8*)(As[buf] + (wr + m * 16 + fr) * 32 + ((fs ^ (fr & 3)) * 8));
#pragma unroll
    for (int n = 0; n < BN / 32; ++n)
      bfr[n] = *(const short8*)(Bs[buf] + (wc + n * 16 + fr) * 32 + ((fs ^ (fr & 3)) * 8));
#pragma unroll
    for (int m = 0; m < 4; ++m)
#pragma unroll
      for (int n = 0; n < BN / 32; ++n)
        acc[m][n] = MFMA_BF16(af[m], bfr[n], acc[m][n], 0, 0, 0);
    __syncthreads();                // vmcnt(0)+barrier: next tile staged, this buf free
    buf ^= 1;
  }
#pragma unroll
  for (int m = 0; m < 4; ++m)
#pragma unroll
    for (int n = 0; n < BN / 32; ++n)
#pragma unroll
      for (int j = 0; j < 4; ++j)
        C[(brow + wr + m * 16 + fs * 4 + j) * (size_t)N + bcol + wc + n * 16 + fr] = acc[m][n][j];
}

// ---------------- fused split-K reduce + QK-RMSNorm + RoPE + head-major scatter ----------------
// qkv partials: qkvA/qkvB [N][3072] fp32 (q 0:2048 | k 2048:2560 | v 2560:3072); row = A + B
// qb: [H][N][64] bf16 (Q pre-scaled by D^-0.5 * log2e) ; kb: [KV][N][64] ; vbt: [KV][64][N]
__global__ __launch_bounds__(256) void prep_kernel(const float* __restrict__ qkv,
                                                   const float* __restrict__ qw,
                                                   const float* __restrict__ kw,
                                                   const float* __restrict__ cosT,
                                                   const float* __restrict__ sinT,
                                                   short* __restrict__ qb,
                                                   short* __restrict__ kb,
                                                   short* __restrict__ vbt) {
  const int n = blockIdx.x, t = threadIdx.x;
  const int w = t >> 6, lane = t & 63;
  __shared__ float redq[4], redk[4];
  const float* rowA = qkv + (size_t)n * 3072;
  const float* rowB = rowA + 6291456;  // second z-partial
  const float* cT = cosT + n * 32;
  const float* sT = sinT + n * 32;
  // --- Q: 2048 elems, 8/thread, norm over full 2048 ---
  const float4* r4a = (const float4*)rowA;
  const float4* r4b = (const float4*)rowB;
  float4 a0 = r4a[t * 2], a1 = r4b[t * 2];
  float4 b0 = r4a[t * 2 + 1], b1 = r4b[t * 2 + 1];
  float4 a = make_float4(a0.x + a1.x, a0.y + a1.y, a0.z + a1.z, a0.w + a1.w);
  float4 b = make_float4(b0.x + b1.x, b0.y + b1.y, b0.z + b1.z, b0.w + b1.w);
  float ss = a.x*a.x + a.y*a.y + a.z*a.z + a.w*a.w + b.x*b.x + b.y*b.y + b.z*b.z + b.w*b.w;
#pragma unroll
  for (int off = 32; off > 0; off >>= 1) ss += __shfl_xor(ss, off);
  if (lane == 0) redq[w] = ss;
  __syncthreads();
  // fold D^-0.5 and log2(e) (scores in log2-domain for exp2-based softmax)
  float rsq = rsqrtf((redq[0] + redq[1] + redq[2] + redq[3]) * (1.0f / 2048.f) + 1e-6f)
              * 0.125f * 1.44269504088896f;
  const int base = t * 8;
  float y[8] = {a.x, a.y, a.z, a.w, b.x, b.y, b.z, b.w};
#pragma unroll
  for (int e = 0; e < 8; ++e) y[e] *= rsq * qw[base + e];
  short8 ov;
  const int dbase = base & 63;
#pragma unroll
  for (int p = 0; p < 4; ++p) {
    float c = cT[(dbase >> 1) + p], s = sT[(dbase >> 1) + p];
    float x1 = y[2 * p], x2 = y[2 * p + 1];
    ov[2 * p]     = (short)f2bf(x1 * c - x2 * s);
    ov[2 * p + 1] = (short)f2bf(x1 * s + x2 * c);
  }
  const int h = base >> 6;
  *(short8*)(qb + ((size_t)h * 2048 + n) * 64 + dbase) = ov;
  // --- K: 512 elems, 2/thread, norm over full 512 ---
  const int ki = t * 2;
  float2 k0 = *(const float2*)(rowA + 2048 + ki);
  float2 k1 = *(const float2*)(rowB + 2048 + ki);
  float2 kv2 = make_float2(k0.x + k1.x, k0.y + k1.y);
  float ssk = kv2.x * kv2.x + kv2.y * kv2.y;
#pragma unroll
  for (int off = 32; off > 0; off >>= 1) ssk += __shfl_xor(ssk, off);
  if (lane == 0) redk[w] = ssk;
  __syncthreads();
  float rsk = rsqrtf((redk[0] + redk[1] + redk[2] + redk[3]) * (1.0f / 512.f) + 1e-6f);
  float z0 = kv2.x * rsk * kw[ki], z1 = kv2.y * rsk * kw[ki + 1];
  const int kd = ki & 63, kvh = ki >> 6;
  {
    float c = cT[kd >> 1], s = sT[kd >> 1];
    ushort2 o2 = make_ushort2(f2bf(z0 * c - z1 * s), f2bf(z0 * s + z1 * c));
    *(ushort2*)(kb + ((size_t)kvh * 2048 + n) * 64 + kd) = o2;
  }
  // --- V: bf16 + transpose store [KV][64][N] ---
  float2 v0 = *(const float2*)(rowA + 2560 + ki);
  float2 v1 = *(const float2*)(rowB + 2560 + ki);
  vbt[((size_t)kvh * 64 + kd) * 2048 + n]       = (short)f2bf(v0.x + v1.x);
  vbt[((size_t)kvh * 64 + kd + 1) * 2048 + n]   = (short)f2bf(v0.y + v1.y);
}

// ---------------- causal GQA flash attention v11: max-free softmax ----------------
// 1024 blocks (head, qblk) longest-first; 4 waves * 16 q-rows; KVBLK=64; LDS 40KB -> 4 blocks/CU.
// K/V double-buffered in LDS (global_load_lds w=16, pre-swizzled src).
// Swapped MFMA(K,Q); softmax uses NO running max: softmax is shift-invariant and
// RMSNorm'd QK scores are |sc|<~10 in log2-domain, so P=exp2(sc) directly (<=2^10,
// l<=2^21 in f32 — no overflow; bf16 relative error is scale-invariant).
// Removes: 15-fmax serial tree, 2 shfl, defer-branch, 16 subs (~35 VALU ops/tile).
__global__ __launch_bounds__(256, 4) void attn_kernel(const short* __restrict__ qb,
                                                      const short* __restrict__ kb,
                                                      const short* __restrict__ vbt,
                                                      short* __restrict__ ab) {
  const int bid = blockIdx.x;
  const int h = bid & 31;
  const int qblk = 31 - (bid >> 5);       // longest blocks dispatch first
  const int kvh = h >> 2;                 // G=4
  const int tid = threadIdx.x;
  const int w = tid >> 6, lane = tid & 63;
  const int fr = lane & 15, fs = lane >> 4;
  const int q0w = qblk * 64 + w * 16;
  const int q_lane = q0w + fr;            // this lane's q row
  __shared__ __align__(16) short Ks[2][64][64];  // [buf][kv][d], chunk c holds global chunk c^(kv&7)
  __shared__ __align__(16) short Vs[2][64][64];  // [buf][d][kv], chunk c holds global chunk c^(d&7)
  __shared__ __align__(16) short Ps[4][16][64];  // per-wave P[q][kv], u64-slot swizzled by (q&7)<<1
  const short* Kb = kb + (size_t)kvh * 2048 * 64;
  const short* Vb = vbt + (size_t)kvh * 64 * 2048;
  short8 qf[2];
  {
    const short* qrow = qb + ((size_t)h * 2048 + q_lane) * 64;
    qf[0] = *(const short8*)(qrow + fs * 8);
    qf[1] = *(const short8*)(qrow + 32 + fs * 8);
  }
  short8 ones8;
#pragma unroll
  for (int e = 0; e < 8; ++e) ones8[e] = (short)0x3F80;  // bf16 1.0
  f32x4 accO[4] = {};                     // O^T: lane q=fr, d = dt*16 + fs*4 + j
  f32x4 lacc = {};                        // row-sum via ones-MFMA (all regs equal)
  short* prow = &Ps[w][fr][0];
  const int swz = (fr & 7) << 1;          // u64-slot XOR (bit0 free -> b128 reads contiguous)

  const int rS = lane >> 3;               // staging row within 8-row strip
  const int cS = (lane & 7) ^ rS;         // pre-swizzled source chunk
  auto stage = [&](int sb, int kv0s) {
#pragma unroll
    for (int i = 0; i < 2; ++i) {
      int r = i * 32 + w * 8 + rS;        // r & 7 == rS
      __builtin_amdgcn_global_load_lds(
          (__attribute__((address_space(1))) void*)(Kb + (size_t)(kv0s + r) * 64 + cS * 8),
          (__attribute__((address_space(3))) void*)(&Ks[sb][0][0] + i * 2048 + w * 512), 16, 0, 0);
      __builtin_amdgcn_global_load_lds(
          (__attribute__((address_space(1))) void*)(Vb + (size_t)r * 2048 + kv0s + cS * 8),
          (__attribute__((address_space(3))) void*)(&Vs[sb][0][0] + i * 2048 + w * 512), 16, 0, 0);
    }
  };

  const int ntiles = qblk + 1;
  int buf = 0;
  stage(0, 0);
  __syncthreads();
  for (int t = 0; t < ntiles; ++t) {
    const int kv0 = t * 64;
    if (t + 1 < ntiles) stage(buf ^ 1, (t + 1) * 64);
    const short* KsB = &Ks[buf][0][0];
    const short* VsB = &Vs[buf][0][0];
    const int sw = (fr & 7);
    // ---- QK^T swapped: sc[ct][j] = S[kv=kv0+ct*16+fs*4+j][q=q_lane] (log2-domain) ----
    f32x4 sc[4];
#pragma unroll
    for (int ct = 0; ct < 4; ++ct) {
      const int rk = ct * 16 + fr;
      short8 kf0 = *(const short8*)(KsB + rk * 64 + ((fs ^ sw) * 8));
      short8 kf1 = *(const short8*)(KsB + rk * 64 + (((4 + fs) ^ sw) * 8));
      f32x4 a = {};
      a = MFMA_BF16(kf0, qf[0], a, 0, 0, 0);
      a = MFMA_BF16(kf1, qf[1], a, 0, 0, 0);
      sc[ct] = a;
    }
    // ---- causal mask (diagonal tile only): kv > q -> P=exp2(-1e30)=0 ----
    if (t == qblk) {
#pragma unroll
      for (int ct = 0; ct < 4; ++ct) {
        const int kvb = kv0 + ct * 16 + fs * 4;
#pragma unroll
        for (int j = 0; j < 4; ++j)
          if (kvb + j > q_lane) sc[ct][j] = -1e30f;
      }
    }
    // ---- P = exp2(sc) (no max subtraction); cvt_pk pack; 4x swizzled ds_write_b64 ----
#pragma unroll
    for (int ct = 0; ct < 4; ++ct) {
      uint2 pk;
      pk.x = cvtpk(exp2f(sc[ct][0]), exp2f(sc[ct][1]));
      pk.y = cvtpk(exp2f(sc[ct][2]), exp2f(sc[ct][3]));
      *(uint2*)(prow + (((ct * 4 + fs) ^ swz) * 4)) = pk;
    }
    // ---- PV + row-sum: pa = B-frag of P^T (lane fr <-> q, elements fs*8+j <-> kv) ----
    short8 pa[2];
#pragma unroll
    for (int s = 0; s < 2; ++s)
      pa[s] = *(const short8*)(prow + (((s * 8 + fs * 2) ^ swz) * 4));
    __builtin_amdgcn_s_setprio(1);
    lacc = MFMA_BF16(ones8, pa[0], lacc, 0, 0, 0);
    lacc = MFMA_BF16(ones8, pa[1], lacc, 0, 0, 0);
#pragma unroll
    for (int dt = 0; dt < 4; ++dt) {
      const int rv = dt * 16 + fr;
      short8 vf0 = *(const short8*)(VsB + rv * 64 + ((fs ^ sw) * 8));
      short8 vf1 = *(const short8*)(VsB + rv * 64 + (((4 + fs) ^ sw) * 8));
      accO[dt] = MFMA_BF16(vf0, pa[0], accO[dt], 0, 0, 0);
      accO[dt] = MFMA_BF16(vf1, pa[1], accO[dt], 0, 0, 0);
    }
    __builtin_amdgcn_s_setprio(0);
    __syncthreads();
    buf ^= 1;
  }
  // ---- epilogue: O = O^T normalized; packed 8B stores ----
  const float inv = 1.0f / lacc[0];
  short* orow = ab + (size_t)q_lane * 2048 + h * 64;
#pragma unroll
  for (int dt = 0; dt < 4; ++dt) {
    uint2 o;
    o.x = cvtpk(accO[dt][0] * inv, accO[dt][1] * inv);
    o.y = cvtpk(accO[dt][2] * inv, accO[dt][3] * inv);
    *(uint2*)(orow + dt * 16 + fs * 4) = o;
  }
}

extern "C" void kernel_launch(void* const* d_in, const int* in_sizes, int n_in,
                              void* d_out, int out_size, void* d_ws, size_t ws_size,
                              hipStream_t stream) {
  const float* x  = (const float*)d_in[0];
  const float* wq = (const float*)d_in[1];
  const float* wk = (const float*)d_in[2];
  const float* wv = (const float*)d_in[3];
  const float* wo = (const float*)d_in[4];
  const float* qw = (const float*)d_in[5];
  const float* kw = (const float*)d_in[6];
  float* out = (float*)d_out;
  char* ws = (char*)d_ws;
  short* xb    = (short*)(ws + 0);          // 8 MB  : x bf16, then attn-out bf16
  short* wb    = (short*)(ws + 8388608);    // 12 MB : [wq;wk;wv] bf16 [3072][2048]
  short* wob   = (short*)(ws + 20971520);   // 8 MB  : wo bf16
  float* qkvfA = (float*)(ws + 29360128);   // 24 MB : qkv z0 partial [2048][3072] f32
  float* qkvfB = (float*)(ws + 54525952);   // 24 MB : qkv z1 partial (contiguous after A)
  short* qb    = (short*)(ws + 79691776);   // 8 MB  : q roped+scaled [32][2048][64]
  short* kb    = (short*)(ws + 88080384);   // 2 MB  : k roped [8][2048][64]
  short* vbt   = (short*)(ws + 90177536);   // 2 MB  : v^T [8][64][2048]
  float* cosT  = (float*)(ws + 92274688);   // 256 KB
  float* sinT  = (float*)(ws + 92536832);   // 256 KB  (total ~88.5 MB)
  short* ab = xb;
  (void)qkvfB; (void)ws_size;

  f2b5_kernel<<<14336, 256, 0, stream>>>(x, wq, wk, wv, wo,
                                         (unsigned short*)xb, (unsigned short*)wb,
                                         (unsigned short*)wob);
  trig_kernel<<<256, 256, 0, stream>>>(cosT, sinT);
  gemm_bt<128><<<dim3(24, 16, 2), 256, 0, stream>>>(xb, wb, qkvfA, 2048, 3072, 2048, 1024);
  prep_kernel<<<2048, 256, 0, stream>>>(qkvfA, qw, kw, cosT, sinT, qb, kb, vbt);
  attn_kernel<<<1024, 256, 0, stream>>>(qb, kb, vbt, ab);
  gemm_bt<64><<<dim3(32, 16, 1), 256, 0, stream>>>(ab, wob, out, 2048, 2048, 2048, 2048);
}

// Round 15
// 139.815 us; speedup vs baseline: 1.4436x; 1.0286x over previous
//
#include <hip/hip_runtime.h>

typedef __attribute__((ext_vector_type(8))) short short8;
typedef __attribute__((ext_vector_type(4))) float f32x4;

#define MFMA_BF16 __builtin_amdgcn_mfma_f32_16x16x32_bf16

__device__ __forceinline__ unsigned short f2bf(float f) {
  unsigned u = __builtin_bit_cast(unsigned, f);
  u += 0x7fffu + ((u >> 16) & 1u);
  return (unsigned short)(u >> 16);
}

__device__ __forceinline__ unsigned cvtpk(float a, float b) {  // lo=bf16(a), hi=bf16(b)
  unsigned r;
  asm("v_cvt_pk_bf16_f32 %0, %1, %2" : "=v"(r) : "v"(a), "v"(b));
  return r;
}

__device__ __forceinline__ float b2f(short s) {
  return __builtin_bit_cast(float, ((unsigned)(unsigned short)s) << 16);
}

// ---------------- fused fp32 -> bf16 convert for all 5 inputs ----------------
__global__ __launch_bounds__(256) void f2b5_kernel(const float* __restrict__ x,
                                                   const float* __restrict__ wq,
                                                   const float* __restrict__ wk,
                                                   const float* __restrict__ wv,
                                                   const float* __restrict__ wo,
                                                   unsigned short* __restrict__ xb,
                                                   unsigned short* __restrict__ wb,
                                                   unsigned short* __restrict__ wob) {
  const int b = blockIdx.x;
  const float* src;
  unsigned short* dst;
  int base;
  if (b < 4096)      { src = x;  dst = xb;                base = b; }
  else if (b < 8192) { src = wq; dst = wb;                base = b - 4096; }
  else if (b < 9216) { src = wk; dst = wb + 2048 * 2048;  base = b - 8192; }
  else if (b < 10240){ src = wv; dst = wb + 2560 * 2048;  base = b - 9216; }
  else               { src = wo; dst = wob;               base = b - 10240; }
  const int i = base * 256 + threadIdx.x;
  const float4 v = ((const float4*)src)[i];
  ushort4 o = make_ushort4(f2bf(v.x), f2bf(v.y), f2bf(v.z), f2bf(v.w));
  ((ushort4*)dst)[i] = o;
}

// ---------------- RoPE trig table: [N][32] cos/sin (f64 once, tiny) ----------------
__global__ __launch_bounds__(256) void trig_kernel(float* __restrict__ cosT, float* __restrict__ sinT) {
  int i = blockIdx.x * 256 + threadIdx.x;  // [0, 2048*32)
  int n = i >> 5, f = i & 31;
  double ang = (double)n * pow(10000.0, -(double)f / 32.0);
  cosT[i] = (float)cos(ang);
  sinT[i] = (float)sin(ang);
}

// ---------------- bf16 NT GEMM, 2-phase double-buffered, tile 128 x BN ----------------
// C_z[M][N] = A[M][Kchunk_z] * B[N][Kchunk_z]^T ; z-slice writes C + z*M*N (plain stores).
// BF16OUT: partials stored bf16 (halves split-K write traffic; ~0.4% rel rounding).
// LDS chunk-XOR swizzle: LDS chunk c of row r holds global chunk c^(r&3) (pre-swizzled src).
template <int BN, bool BF16OUT>
__global__ __launch_bounds__(256) void gemm_bt(const short* __restrict__ A,
                                               const short* __restrict__ B,
                                               void* __restrict__ Cv,
                                               int M, int N, int K, int KC) {
  __shared__ __align__(16) short As[2][128 * 32];
  __shared__ __align__(16) short Bs[2][BN * 32];
  const int tid = threadIdx.x;
  const int w = tid >> 6, lane = tid & 63;
  const int fr = lane & 15, fs = lane >> 4;
  const size_t brow = (size_t)blockIdx.y * 128, bcol = (size_t)blockIdx.x * BN;
  const int wr = (w >> 1) * 64, wc = (w & 1) * (BN / 2);
  const int lr = tid >> 2;          // staging row 0..63 (+64 for 2nd issue)
  const int lcS = ((tid & 3) ^ (lr & 3)) * 8;  // pre-swizzled source chunk (8 bf16 = 16B)
  const int ks = blockIdx.z * KC;
  const size_t zoff = (size_t)blockIdx.z * ((size_t)M * N);
  const short* ga = A + (brow + lr) * (size_t)K + lcS + ks;
  const short* gb = B + (bcol + lr) * (size_t)K + lcS + ks;
  f32x4 acc[4][BN / 32] = {};

  auto stage = [&](int sb, int k0) {
    short* lA = As[sb] + w * 512;   // wave-uniform LDS dest (HW: base + lane*16B)
    short* lB = Bs[sb] + w * 512;
    __builtin_amdgcn_global_load_lds((__attribute__((address_space(1))) void*)(ga + k0),
                                     (__attribute__((address_space(3))) void*)(lA), 16, 0, 0);
    __builtin_amdgcn_global_load_lds((__attribute__((address_space(1))) void*)(ga + (size_t)64 * K + k0),
                                     (__attribute__((address_space(3))) void*)(lA + 2048), 16, 0, 0);
    __builtin_amdgcn_global_load_lds((__attribute__((address_space(1))) void*)(gb + k0),
                                     (__attribute__((address_space(3))) void*)(lB), 16, 0, 0);
    if (BN == 128)
      __builtin_amdgcn_global_load_lds((__attribute__((address_space(1))) void*)(gb + (size_t)64 * K + k0),
                                       (__attribute__((address_space(3))) void*)(lB + 2048), 16, 0, 0);
  };

  const int nk = KC >> 5;
  stage(0, 0);
  __syncthreads();                  // drain prologue loads
  int buf = 0;
  for (int t = 0; t < nk; ++t) {
    if (t + 1 < nk) stage(buf ^ 1, (t + 1) * 32);  // issue next-tile loads (in flight over MFMA)
    short8 af[4], bfr[BN / 32];
#pragma unroll
    for (int m = 0; m < 4; ++m)
      af[m] = *(const short8*)(As[buf] + (wr + m * 16 + fr) * 32 + ((fs ^ (fr & 3)) * 8));
#pragma unroll
    for (int n = 0; n < BN / 32; ++n)
      bfr[n] = *(const short8*)(Bs[buf] + (wc + n * 16 + fr) * 32 + ((fs ^ (fr & 3)) * 8));
#pragma unroll
    for (int m = 0; m < 4; ++m)
#pragma unroll
      for (int n = 0; n < BN / 32; ++n)
        acc[m][n] = MFMA_BF16(af[m], bfr[n], acc[m][n], 0, 0, 0);
    __syncthreads();                // vmcnt(0)+barrier: next tile staged, this buf free
    buf ^= 1;
  }
#pragma unroll
  for (int m = 0; m < 4; ++m)
#pragma unroll
    for (int n = 0; n < BN / 32; ++n)
#pragma unroll
      for (int j = 0; j < 4; ++j) {
        const size_t idx = zoff + (brow + wr + m * 16 + fs * 4 + j) * (size_t)N + bcol + wc + n * 16 + fr;
        if (BF16OUT) ((short*)Cv)[idx] = (short)f2bf(acc[m][n][j]);
        else         ((float*)Cv)[idx] = acc[m][n][j];
      }
}

// ---------------- fused split-K reduce + QK-RMSNorm + RoPE + head-major scatter ----------------
// qkv partials (bf16): rowA/rowB [N][3072] (q 0:2048 | k 2048:2560 | v 2560:3072); row = A + B
// qb: [H][N][64] bf16 (Q pre-scaled by D^-0.5 * log2e) ; kb: [KV][N][64] ; vbt: [KV][64][N]
__global__ __launch_bounds__(256) void prep_kernel(const short* __restrict__ qkvb,
                                                   const float* __restrict__ qw,
                                                   const float* __restrict__ kw,
                                                   const float* __restrict__ cosT,
                                                   const float* __restrict__ sinT,
                                                   short* __restrict__ qb,
                                                   short* __restrict__ kb,
                                                   short* __restrict__ vbt) {
  const int n = blockIdx.x, t = threadIdx.x;
  const int w = t >> 6, lane = t & 63;
  __shared__ float redq[4], redk[4];
  const short* rowA = qkvb + (size_t)n * 3072;
  const short* rowB = rowA + 6291456;  // second z-partial (3072*2048 elements)
  const float* cT = cosT + n * 32;
  const float* sT = sinT + n * 32;
  // --- Q: 2048 elems, 8/thread, norm over full 2048 ---
  const short8 qa = *(const short8*)(rowA + t * 8);
  const short8 qbv = *(const short8*)(rowB + t * 8);
  float y[8];
#pragma unroll
  for (int e = 0; e < 8; ++e) y[e] = b2f(qa[e]) + b2f(qbv[e]);
  float ss = 0.f;
#pragma unroll
  for (int e = 0; e < 8; ++e) ss += y[e] * y[e];
#pragma unroll
  for (int off = 32; off > 0; off >>= 1) ss += __shfl_xor(ss, off);
  if (lane == 0) redq[w] = ss;
  __syncthreads();
  // fold D^-0.5 and log2(e) (scores in log2-domain for exp2-based softmax)
  float rsq = rsqrtf((redq[0] + redq[1] + redq[2] + redq[3]) * (1.0f / 2048.f) + 1e-6f)
              * 0.125f * 1.44269504088896f;
  const int base = t * 8;
#pragma unroll
  for (int e = 0; e < 8; ++e) y[e] *= rsq * qw[base + e];
  short8 ov;
  const int dbase = base & 63;
#pragma unroll
  for (int p = 0; p < 4; ++p) {
    float c = cT[(dbase >> 1) + p], s = sT[(dbase >> 1) + p];
    float x1 = y[2 * p], x2 = y[2 * p + 1];
    ov[2 * p]     = (short)f2bf(x1 * c - x2 * s);
    ov[2 * p + 1] = (short)f2bf(x1 * s + x2 * c);
  }
  const int h = base >> 6;
  *(short8*)(qb + ((size_t)h * 2048 + n) * 64 + dbase) = ov;
  // --- K: 512 elems, 2/thread, norm over full 512 ---
  const int ki = t * 2;
  float kx = b2f(rowA[2048 + ki]) + b2f(rowB[2048 + ki]);
  float ky = b2f(rowA[2049 + ki]) + b2f(rowB[2049 + ki]);
  float ssk = kx * kx + ky * ky;
#pragma unroll
  for (int off = 32; off > 0; off >>= 1) ssk += __shfl_xor(ssk, off);
  if (lane == 0) redk[w] = ssk;
  __syncthreads();
  float rsk = rsqrtf((redk[0] + redk[1] + redk[2] + redk[3]) * (1.0f / 512.f) + 1e-6f);
  float z0 = kx * rsk * kw[ki], z1 = ky * rsk * kw[ki + 1];
  const int kd = ki & 63, kvh = ki >> 6;
  {
    float c = cT[kd >> 1], s = sT[kd >> 1];
    ushort2 o2 = make_ushort2(f2bf(z0 * c - z1 * s), f2bf(z0 * s + z1 * c));
    *(ushort2*)(kb + ((size_t)kvh * 2048 + n) * 64 + kd) = o2;
  }
  // --- V: bf16 + transpose store [KV][64][N] ---
  float vx = b2f(rowA[2560 + ki]) + b2f(rowB[2560 + ki]);
  float vy = b2f(rowA[2561 + ki]) + b2f(rowB[2561 + ki]);
  vbt[((size_t)kvh * 64 + kd) * 2048 + n]       = (short)f2bf(vx);
  vbt[((size_t)kvh * 64 + kd + 1) * 2048 + n]   = (short)f2bf(vy);
}

// ---------------- causal GQA flash attention v11: max-free softmax (41.2us proven) ----------------
// 1024 blocks (head, qblk) longest-first; 4 waves * 16 q-rows; KVBLK=64; LDS 40KB -> 4 blocks/CU.
// K/V double-buffered in LDS (global_load_lds w=16, pre-swizzled src).
// Swapped MFMA(K,Q); NO running max (softmax shift-invariance + RMSNorm'd score bound).
__global__ __launch_bounds__(256, 4) void attn_kernel(const short* __restrict__ qb,
                                                      const short* __restrict__ kb,
                                                      const short* __restrict__ vbt,
                                                      short* __restrict__ ab) {
  const int bid = blockIdx.x;
  const int h = bid & 31;
  const int qblk = 31 - (bid >> 5);       // longest blocks dispatch first
  const int kvh = h >> 2;                 // G=4
  const int tid = threadIdx.x;
  const int w = tid >> 6, lane = tid & 63;
  const int fr = lane & 15, fs = lane >> 4;
  const int q0w = qblk * 64 + w * 16;
  const int q_lane = q0w + fr;            // this lane's q row
  __shared__ __align__(16) short Ks[2][64][64];  // [buf][kv][d], chunk c holds global chunk c^(kv&7)
  __shared__ __align__(16) short Vs[2][64][64];  // [buf][d][kv], chunk c holds global chunk c^(d&7)
  __shared__ __align__(16) short Ps[4][16][64];  // per-wave P[q][kv], u64-slot swizzled by (q&7)<<1
  const short* Kb = kb + (size_t)kvh * 2048 * 64;
  const short* Vb = vbt + (size_t)kvh * 64 * 2048;
  short8 qf[2];
  {
    const short* qrow = qb + ((size_t)h * 2048 + q_lane) * 64;
    qf[0] = *(const short8*)(qrow + fs * 8);
    qf[1] = *(const short8*)(qrow + 32 + fs * 8);
  }
  short8 ones8;
#pragma unroll
  for (int e = 0; e < 8; ++e) ones8[e] = (short)0x3F80;  // bf16 1.0
  f32x4 accO[4] = {};                     // O^T: lane q=fr, d = dt*16 + fs*4 + j
  f32x4 lacc = {};                        // row-sum via ones-MFMA (all regs equal)
  short* prow = &Ps[w][fr][0];
  const int swz = (fr & 7) << 1;          // u64-slot XOR (bit0 free -> b128 reads contiguous)

  const int rS = lane >> 3;               // staging row within 8-row strip
  const int cS = (lane & 7) ^ rS;         // pre-swizzled source chunk
  auto stage = [&](int sb, int kv0s) {
#pragma unroll
    for (int i = 0; i < 2; ++i) {
      int r = i * 32 + w * 8 + rS;        // r & 7 == rS
      __builtin_amdgcn_global_load_lds(
          (__attribute__((address_space(1))) void*)(Kb + (size_t)(kv0s + r) * 64 + cS * 8),
          (__attribute__((address_space(3))) void*)(&Ks[sb][0][0] + i * 2048 + w * 512), 16, 0, 0);
      __builtin_amdgcn_global_load_lds(
          (__attribute__((address_space(1))) void*)(Vb + (size_t)r * 2048 + kv0s + cS * 8),
          (__attribute__((address_space(3))) void*)(&Vs[sb][0][0] + i * 2048 + w * 512), 16, 0, 0);
    }
  };

  const int ntiles = qblk + 1;
  int buf = 0;
  stage(0, 0);
  __syncthreads();
  for (int t = 0; t < ntiles; ++t) {
    const int kv0 = t * 64;
    if (t + 1 < ntiles) stage(buf ^ 1, (t + 1) * 64);
    const short* KsB = &Ks[buf][0][0];
    const short* VsB = &Vs[buf][0][0];
    const int sw = (fr & 7);
    // ---- QK^T swapped: sc[ct][j] = S[kv=kv0+ct*16+fs*4+j][q=q_lane] (log2-domain) ----
    f32x4 sc[4];
#pragma unroll
    for (int ct = 0; ct < 4; ++ct) {
      const int rk = ct * 16 + fr;
      short8 kf0 = *(const short8*)(KsB + rk * 64 + ((fs ^ sw) * 8));
      short8 kf1 = *(const short8*)(KsB + rk * 64 + (((4 + fs) ^ sw) * 8));
      f32x4 a = {};
      a = MFMA_BF16(kf0, qf[0], a, 0, 0, 0);
      a = MFMA_BF16(kf1, qf[1], a, 0, 0, 0);
      sc[ct] = a;
    }
    // ---- causal mask (diagonal tile only): kv > q -> P=exp2(-1e30)=0 ----
    if (t == qblk) {
#pragma unroll
      for (int ct = 0; ct < 4; ++ct) {
        const int kvb = kv0 + ct * 16 + fs * 4;
#pragma unroll
        for (int j = 0; j < 4; ++j)
          if (kvb + j > q_lane) sc[ct][j] = -1e30f;
      }
    }
    // ---- P = exp2(sc) (no max subtraction); cvt_pk pack; 4x swizzled ds_write_b64 ----
#pragma unroll
    for (int ct = 0; ct < 4; ++ct) {
      uint2 pk;
      pk.x = cvtpk(exp2f(sc[ct][0]), exp2f(sc[ct][1]));
      pk.y = cvtpk(exp2f(sc[ct][2]), exp2f(sc[ct][3]));
      *(uint2*)(prow + (((ct * 4 + fs) ^ swz) * 4)) = pk;
    }
    // ---- PV + row-sum: pa = B-frag of P^T (lane fr <-> q, elements fs*8+j <-> kv) ----
    short8 pa[2];
#pragma unroll
    for (int s = 0; s < 2; ++s)
      pa[s] = *(const short8*)(prow + (((s * 8 + fs * 2) ^ swz) * 4));
    __builtin_amdgcn_s_setprio(1);
    lacc = MFMA_BF16(ones8, pa[0], lacc, 0, 0, 0);
    lacc = MFMA_BF16(ones8, pa[1], lacc, 0, 0, 0);
#pragma unroll
    for (int dt = 0; dt < 4; ++dt) {
      const int rv = dt * 16 + fr;
      short8 vf0 = *(const short8*)(VsB + rv * 64 + ((fs ^ sw) * 8));
      short8 vf1 = *(const short8*)(VsB + rv * 64 + (((4 + fs) ^ sw) * 8));
      accO[dt] = MFMA_BF16(vf0, pa[0], accO[dt], 0, 0, 0);
      accO[dt] = MFMA_BF16(vf1, pa[1], accO[dt], 0, 0, 0);
    }
    __builtin_amdgcn_s_setprio(0);
    __syncthreads();
    buf ^= 1;
  }
  // ---- epilogue: O = O^T normalized; packed 8B stores ----
  const float inv = 1.0f / lacc[0];
  short* orow = ab + (size_t)q_lane * 2048 + h * 64;
#pragma unroll
  for (int dt = 0; dt < 4; ++dt) {
    uint2 o;
    o.x = cvtpk(accO[dt][0] * inv, accO[dt][1] * inv);
    o.y = cvtpk(accO[dt][2] * inv, accO[dt][3] * inv);
    *(uint2*)(orow + dt * 16 + fs * 4) = o;
  }
}

extern "C" void kernel_launch(void* const* d_in, const int* in_sizes, int n_in,
                              void* d_out, int out_size, void* d_ws, size_t ws_size,
                              hipStream_t stream) {
  const float* x  = (const float*)d_in[0];
  const float* wq = (const float*)d_in[1];
  const float* wk = (const float*)d_in[2];
  const float* wv = (const float*)d_in[3];
  const float* wo = (const float*)d_in[4];
  const float* qw = (const float*)d_in[5];
  const float* kw = (const float*)d_in[6];
  float* out = (float*)d_out;
  char* ws = (char*)d_ws;
  short* xb    = (short*)(ws + 0);          // 8 MB  : x bf16, then attn-out bf16
  short* wb    = (short*)(ws + 8388608);    // 12 MB : [wq;wk;wv] bf16 [3072][2048]
  short* wob   = (short*)(ws + 20971520);   // 8 MB  : wo bf16
  short* qkvbA = (short*)(ws + 29360128);   // 12 MB : qkv z0 partial [2048][3072] bf16
  short* qkvbB = (short*)(ws + 41943040);   // 12 MB : qkv z1 partial (contiguous after A)
  short* qb    = (short*)(ws + 79691776);   // 8 MB  : q roped+scaled [32][2048][64]
  short* kb    = (short*)(ws + 88080384);   // 2 MB  : k roped [8][2048][64]
  short* vbt   = (short*)(ws + 90177536);   // 2 MB  : v^T [8][64][2048]
  float* cosT  = (float*)(ws + 92274688);   // 256 KB
  float* sinT  = (float*)(ws + 92536832);   // 256 KB  (total ~88.5 MB)
  short* ab = xb;
  (void)qkvbB; (void)ws_size;

  f2b5_kernel<<<14336, 256, 0, stream>>>(x, wq, wk, wv, wo,
                                         (unsigned short*)xb, (unsigned short*)wb,
                                         (unsigned short*)wob);
  trig_kernel<<<256, 256, 0, stream>>>(cosT, sinT);
  gemm_bt<128, true><<<dim3(24, 16, 2), 256, 0, stream>>>(xb, wb, qkvbA, 2048, 3072, 2048, 1024);
  prep_kernel<<<2048, 256, 0, stream>>>(qkvbA, qw, kw, cosT, sinT, qb, kb, vbt);
  attn_kernel<<<1024, 256, 0, stream>>>(qb, kb, vbt, ab);
  gemm_bt<64, false><<<dim3(32, 16, 1), 256, 0, stream>>>(ab, wob, out, 2048, 2048, 2048, 2048);
}